// Round 2
// baseline (4769.007 us; speedup 1.0000x reference)
//
#include <hip/hip_runtime.h>
#include <hip/hip_bf16.h>

typedef __hip_bfloat16 bf16;

#define NN 50000
#define RR 6
#define EE 32768
#define HH 256
#define FF 16
#define NHEAD 8
#define KV_K 272

struct __align__(8) bf16x4 { bf16 v[4]; };

__device__ __forceinline__ float b2f(bf16 v) { return __bfloat162float(v); }
__device__ __forceinline__ bf16 f2b(float v) { return __float2bfloat16(v); }
__device__ __forceinline__ float gelu_f(float x) { return 0.5f * x * (1.0f + erff(x * 0.7071067811865476f)); }
// monotone float<->uint key for atomicMax on floats (init key = 0 == below all finite keys)
__device__ __forceinline__ unsigned fkey(float f) { unsigned u = __float_as_uint(f); return (u & 0x80000000u) ? ~u : (u | 0x80000000u); }
__device__ __forceinline__ float fdec(unsigned k) { unsigned u = (k & 0x80000000u) ? (k & 0x7fffffffu) : ~k; return __uint_as_float(u); }

// grid-stride zero fill (16B granules) — graph-capture-safe replacement for hipMemsetAsync
__global__ void zero_k(uint4* __restrict__ p, int n16)
{
  const uint4 z = make_uint4(0u, 0u, 0u, 0u);
  for (int i = blockIdx.x * blockDim.x + threadIdx.x; i < n16; i += gridDim.x * blockDim.x)
    p[i] = z;
}

// ---------------------------------------------------------------------------
// Generic tiled GEMM: C[M,NC] = act(A[M,K] @ W[K,NC] + bias)
// BM=BN=64, BK=16, 256 threads, 4x4 microtile per thread, fp32 accumulate.
// RELSPLIT: A is rel_out [RR][NN][HH] viewed as [NN][RR*HH] (k -> (k>>8, k&255)).
// ---------------------------------------------------------------------------
template<typename TA, typename TO, int ACT, bool RELSPLIT>
__global__ __launch_bounds__(256) void gemm_k(
    const TA* __restrict__ A, const float* __restrict__ W,
    const float* __restrict__ bias, TO* __restrict__ C,
    int M, int K, int NC)
{
  __shared__ float As[16][68];   // [k][m], padded
  __shared__ float Ws[16][68];   // [k][n]
  const int tid = threadIdx.x;
  const int row0 = blockIdx.x << 6;
  const int col0 = blockIdx.y << 6;
  const int tx = tid & 15, ty = tid >> 4;
  float acc[4][4] = {};

  const int ar = tid >> 2;            // 0..63  (A tile row)
  const int ac = (tid & 3) << 2;      // 0,4,8,12 (A tile col base)
  const int wk = tid >> 4;            // 0..15  (W tile row)
  const int wc = (tid & 15) << 2;     // 0..60  (W tile col base)

  for (int k0 = 0; k0 < K; k0 += 16) {
    float a0 = 0.f, a1 = 0.f, a2 = 0.f, a3 = 0.f;
    const int grow = row0 + ar;
    if (grow < M) {
      const int k = k0 + ac;
      if constexpr (RELSPLIT) {
        const bf16* p = (const bf16*)A + (size_t)(k >> 8) * ((size_t)NN * HH) + (size_t)grow * HH + (k & 255);
        bf16x4 t = *(const bf16x4*)p;
        a0 = b2f(t.v[0]); a1 = b2f(t.v[1]); a2 = b2f(t.v[2]); a3 = b2f(t.v[3]);
      } else if constexpr (sizeof(TA) == 2) {
        const bf16* p = (const bf16*)A + (size_t)grow * K + k;
        bf16x4 t = *(const bf16x4*)p;
        a0 = b2f(t.v[0]); a1 = b2f(t.v[1]); a2 = b2f(t.v[2]); a3 = b2f(t.v[3]);
      } else {
        const float4 t = *(const float4*)((const float*)A + (size_t)grow * K + k);
        a0 = t.x; a1 = t.y; a2 = t.z; a3 = t.w;
      }
    }
    As[ac + 0][ar] = a0; As[ac + 1][ar] = a1; As[ac + 2][ar] = a2; As[ac + 3][ar] = a3;
    *(float4*)&Ws[wk][wc] = *(const float4*)(W + (size_t)(k0 + wk) * NC + (col0 + wc));
    __syncthreads();
#pragma unroll
    for (int k = 0; k < 16; ++k) {
      const float4 a = *(const float4*)&As[k][ty << 2];
      const float4 b = *(const float4*)&Ws[k][tx << 2];
      acc[0][0] += a.x * b.x; acc[0][1] += a.x * b.y; acc[0][2] += a.x * b.z; acc[0][3] += a.x * b.w;
      acc[1][0] += a.y * b.x; acc[1][1] += a.y * b.y; acc[1][2] += a.y * b.z; acc[1][3] += a.y * b.w;
      acc[2][0] += a.z * b.x; acc[2][1] += a.z * b.y; acc[2][2] += a.z * b.z; acc[2][3] += a.z * b.w;
      acc[3][0] += a.w * b.x; acc[3][1] += a.w * b.y; acc[3][2] += a.w * b.z; acc[3][3] += a.w * b.w;
    }
    __syncthreads();
  }
  const int colb = col0 + (tx << 2);
  const float bs0 = bias[colb + 0], bs1 = bias[colb + 1], bs2 = bias[colb + 2], bs3 = bias[colb + 3];
#pragma unroll
  for (int i = 0; i < 4; ++i) {
    const int grow = row0 + (ty << 2) + i;
    if (grow >= M) continue;
    float v0 = acc[i][0] + bs0, v1 = acc[i][1] + bs1, v2 = acc[i][2] + bs2, v3 = acc[i][3] + bs3;
    if constexpr (ACT == 1) { v0 = gelu_f(v0); v1 = gelu_f(v1); v2 = gelu_f(v2); v3 = gelu_f(v3); }
    if constexpr (sizeof(TO) == 2) {
      bf16x4 o; o.v[0] = f2b(v0); o.v[1] = f2b(v1); o.v[2] = f2b(v2); o.v[3] = f2b(v3);
      *(bf16x4*)((bf16*)C + (size_t)grow * NC + colb) = o;
    } else {
      *(float4*)((float*)C + (size_t)grow * NC + colb) = make_float4(v0, v1, v2, v3);
    }
  }
}

// ---------------------------------------------------------------------------
// Edge-side kernels (per relation)
// ---------------------------------------------------------------------------
__global__ void gather_kv(const float* __restrict__ x, const int* __restrict__ src_idx,
                          const float* __restrict__ eattr, bf16* __restrict__ kv)
{
  const int e = blockIdx.x, t = threadIdx.x;
  const int src = src_idx[e];
  kv[(size_t)e * KV_K + t] = f2b(x[(size_t)src * HH + t]);
  if (t < FF) kv[(size_t)e * KV_K + HH + t] = f2b(eattr[(size_t)e * FF + t]);
}

__global__ void scores_k(const bf16* __restrict__ q, const bf16* __restrict__ k,
                         const int* __restrict__ dst_idx, const float* __restrict__ prior_r,
                         float* __restrict__ scores, unsigned* __restrict__ mkey)
{
  const int e = blockIdx.x, t = threadIdx.x;
  const int dst = dst_idx[e];
  float p = b2f(q[(size_t)dst * HH + t]) * b2f(k[(size_t)e * HH + t]);
#pragma unroll
  for (int off = 16; off > 0; off >>= 1) p += __shfl_down(p, off, 32);
  const int h = t >> 5;
  if ((t & 31) == 0) {
    const float s = p * 0.1767766952966369f * prior_r[h];  // 1/sqrt(32)
    scores[e * NHEAD + h] = s;
    atomicMax(&mkey[dst * NHEAD + h], fkey(s));
  }
}

__global__ void expden_k(const float* __restrict__ scores, const int* __restrict__ dst_idx,
                         const unsigned* __restrict__ mkey, float* __restrict__ ex,
                         float* __restrict__ denom)
{
  const int idx = blockIdx.x * 256 + threadIdx.x;
  if (idx >= EE * NHEAD) return;
  const int e = idx >> 3, h = idx & 7;
  const int dst = dst_idx[e];
  const float m = fdec(mkey[dst * NHEAD + h]);
  const float v = expf(scores[idx] - m);
  ex[idx] = v;
  atomicAdd(&denom[dst * NHEAD + h], v);
}

__global__ void agg_k(const float* __restrict__ ex, const float* __restrict__ denom,
                      const bf16* __restrict__ v, const int* __restrict__ dst_idx,
                      float* __restrict__ agg)
{
  const int e = blockIdx.x, t = threadIdx.x, h = t >> 5;
  const int dst = dst_idx[e];
  const float w = ex[e * NHEAD + h] / (denom[dst * NHEAD + h] + 1e-16f);
  atomicAdd(&agg[(size_t)dst * HH + t], w * b2f(v[(size_t)e * HH + t]));
}

// ---------------------------------------------------------------------------
// inter-relation: logits = h @ W_ir2 + b_ir2, softmax over R; one wave per node
// ---------------------------------------------------------------------------
__global__ void interw_k(const bf16* __restrict__ h, const float* __restrict__ W2,
                         const float* __restrict__ b2, float* __restrict__ interw)
{
  const int wv = threadIdx.x >> 6, ln = threadIdx.x & 63;
  const int n = blockIdx.x * 4 + wv;
  if (n >= NN) return;
  float a[6] = {0.f, 0.f, 0.f, 0.f, 0.f, 0.f};
#pragma unroll
  for (int kq = 0; kq < 4; ++kq) {
    const int k = ln + (kq << 6);
    const float hv = b2f(h[(size_t)n * HH + k]);
#pragma unroll
    for (int j = 0; j < 6; ++j) a[j] += hv * W2[k * 6 + j];
  }
#pragma unroll
  for (int j = 0; j < 6; ++j) {
#pragma unroll
    for (int off = 32; off > 0; off >>= 1) a[j] += __shfl_down(a[j], off, 64);
  }
  if (ln == 0) {
    float l[6], e[6], mx = -1e30f, s = 0.f;
#pragma unroll
    for (int j = 0; j < 6; ++j) { l[j] = a[j] + b2[j]; mx = fmaxf(mx, l[j]); }
#pragma unroll
    for (int j = 0; j < 6; ++j) { e[j] = expf(l[j] - mx); s += e[j]; }
    const float inv = 1.0f / s;
#pragma unroll
    for (int j = 0; j < 6; ++j) interw[(size_t)n * 6 + j] = e[j] * inv;
  }
}

__global__ void interagg_k(const float* __restrict__ interw, const bf16* __restrict__ rel,
                           bf16* __restrict__ comb)
{
  const int n = blockIdx.x, t = threadIdx.x;
  float acc = 0.f;
#pragma unroll
  for (int r = 0; r < 6; ++r)
    acc += interw[(size_t)n * 6 + r] * b2f(rel[(size_t)r * NN * HH + (size_t)n * HH + t]);
  comb[(size_t)n * 512 + t] = f2b(acc);
}

// ---------------------------------------------------------------------------
// Fused meta-path kernel: 8 nodes/block, all in LDS (never materializes [N,3,H])
// ---------------------------------------------------------------------------
#define MG 8
#define GS 8

__global__ __launch_bounds__(256) void meta_k(
    const bf16* __restrict__ rel, const float* __restrict__ Wmp, const float* __restrict__ bmp,
    const float* __restrict__ Wa1, const float* __restrict__ ba1, const float* __restrict__ Wa2,
    const float* __restrict__ gmeta, const float* __restrict__ bmeta, bf16* __restrict__ comb)
{
  __shared__ float paths2[3 * 256 * GS];    // [p][k][g]
  __shared__ float stacked2[3 * 256 * GS];  // [p][j][g]
  __shared__ float attn_l[MG][3];
  __shared__ float red[MG * 3];
  const int tid = threadIdx.x;
  const int nbase = blockIdx.x * MG;
  if (tid < MG * 3) red[tid] = 0.f;

  // A1: coalesced load of rel rows -> tmp[g][p][c] (aliases stacked2)
  float* tmp = stacked2;
  const int r1[3] = {2, 4, 1};
  const int r2[3] = {3, 0, 5};
  for (int idx = tid; idx < MG * 3 * 256; idx += 256) {
    const int g = idx / 768, rem = idx - g * 768, p = rem >> 8, c = rem & 255;
    const int n = nbase + g;
    float v = 0.f;
    if (n < NN) {
      const size_t o = (size_t)n * HH + c;
      v = b2f(rel[(size_t)r1[p] * NN * HH + o]) + b2f(rel[(size_t)r2[p] * NN * HH + o]);
    }
    tmp[idx] = v;
  }
  __syncthreads();
  // A2: transpose -> paths2[p][c][g]
  for (int idx = tid; idx < 3 * 256 * MG; idx += 256) {
    const int p = idx >> 11, rem = idx & 2047, c = rem >> 3, g = rem & 7;
    paths2[(p * 256 + c) * GS + g] = tmp[g * 768 + p * 256 + c];
  }
  __syncthreads();
  // B: stacked[p][j][g] = paths[g][p][:] @ Wmp[p][:,j] + bmp[p][j], j = tid
  {
    const int j = tid;
    float acc[MG][3];
#pragma unroll
    for (int g = 0; g < MG; ++g) { acc[g][0] = 0.f; acc[g][1] = 0.f; acc[g][2] = 0.f; }
    for (int k = 0; k < 256; ++k) {
      const float w0 = Wmp[(size_t)(k * 256) + j];
      const float w1 = Wmp[(size_t)(65536 + k * 256) + j];
      const float w2 = Wmp[(size_t)(131072 + k * 256) + j];
      const float4 pa0 = *(const float4*)&paths2[(0 * 256 + k) * GS + 0];
      const float4 pb0 = *(const float4*)&paths2[(0 * 256 + k) * GS + 4];
      const float4 pa1 = *(const float4*)&paths2[(1 * 256 + k) * GS + 0];
      const float4 pb1 = *(const float4*)&paths2[(1 * 256 + k) * GS + 4];
      const float4 pa2 = *(const float4*)&paths2[(2 * 256 + k) * GS + 0];
      const float4 pb2 = *(const float4*)&paths2[(2 * 256 + k) * GS + 4];
      acc[0][0] += pa0.x * w0; acc[1][0] += pa0.y * w0; acc[2][0] += pa0.z * w0; acc[3][0] += pa0.w * w0;
      acc[4][0] += pb0.x * w0; acc[5][0] += pb0.y * w0; acc[6][0] += pb0.z * w0; acc[7][0] += pb0.w * w0;
      acc[0][1] += pa1.x * w1; acc[1][1] += pa1.y * w1; acc[2][1] += pa1.z * w1; acc[3][1] += pa1.w * w1;
      acc[4][1] += pb1.x * w1; acc[5][1] += pb1.y * w1; acc[6][1] += pb1.z * w1; acc[7][1] += pb1.w * w1;
      acc[0][2] += pa2.x * w2; acc[1][2] += pa2.y * w2; acc[2][2] += pa2.z * w2; acc[3][2] += pa2.w * w2;
      acc[4][2] += pb2.x * w2; acc[5][2] += pb2.y * w2; acc[6][2] += pb2.z * w2; acc[7][2] += pb2.w * w2;
    }
#pragma unroll
    for (int p = 0; p < 3; ++p)
#pragma unroll
      for (int g = 0; g < MG; ++g)
        stacked2[(p * 256 + j) * GS + g] = acc[g][p] + bmp[p * 256 + j];
  }
  __syncthreads();
  // C: t = tanh(stacked @ Wa1 + ba1); logits = t @ Wa2
  {
    const int i = tid & 127;
    const int go = tid >> 7;
    float at[4][3];
#pragma unroll
    for (int g = 0; g < 4; ++g) { at[g][0] = 0.f; at[g][1] = 0.f; at[g][2] = 0.f; }
    for (int jj = 0; jj < 256; ++jj) {
      const float w = Wa1[(size_t)jj * 128 + i];
#pragma unroll
      for (int p = 0; p < 3; ++p) {
        const float4 sv = *(const float4*)&stacked2[(p * 256 + jj) * GS + (go << 2)];
        at[0][p] += sv.x * w; at[1][p] += sv.y * w; at[2][p] += sv.z * w; at[3][p] += sv.w * w;
      }
    }
    const float b1 = ba1[i];
    const float w2v = Wa2[i];
#pragma unroll
    for (int g = 0; g < 4; ++g)
#pragma unroll
      for (int p = 0; p < 3; ++p) {
        float v = tanhf(at[g][p] + b1) * w2v;
#pragma unroll
        for (int off = 32; off > 0; off >>= 1) v += __shfl_down(v, off, 64);
        if ((tid & 63) == 0) atomicAdd(&red[(go * 4 + g) * 3 + p], v);
      }
  }
  __syncthreads();
  if (tid < MG) {
    const float l0 = red[tid * 3 + 0], l1 = red[tid * 3 + 1], l2 = red[tid * 3 + 2];
    const float mx = fmaxf(l0, fmaxf(l1, l2));
    const float e0 = expf(l0 - mx), e1 = expf(l1 - mx), e2 = expf(l2 - mx);
    const float s = 1.0f / (e0 + e1 + e2);
    attn_l[tid][0] = e0 * s; attn_l[tid][1] = e1 * s; attn_l[tid][2] = e2 * s;
  }
  __syncthreads();
  // D: meta = LN(sum_p attn*stacked); one wave per node, 2 nodes per wave
  {
    const int wv = tid >> 6, ln = tid & 63;
#pragma unroll
    for (int gi = 0; gi < 2; ++gi) {
      const int g = wv + (gi << 2);
      const int n = nbase + g;
      const float a0 = attn_l[g][0], a1 = attn_l[g][1], a2 = attn_l[g][2];
      float pre[4], s = 0.f, s2 = 0.f;
#pragma unroll
      for (int q4 = 0; q4 < 4; ++q4) {
        const int j = ln + (q4 << 6);
        const float v = a0 * stacked2[(0 * 256 + j) * GS + g]
                      + a1 * stacked2[(1 * 256 + j) * GS + g]
                      + a2 * stacked2[(2 * 256 + j) * GS + g];
        pre[q4] = v; s += v; s2 += v * v;
      }
#pragma unroll
      for (int off = 32; off > 0; off >>= 1) { s += __shfl_down(s, off, 64); s2 += __shfl_down(s2, off, 64); }
      s = __shfl(s, 0, 64); s2 = __shfl(s2, 0, 64);
      const float mu = s * (1.0f / 256.0f);
      const float var = s2 * (1.0f / 256.0f) - mu * mu;
      const float rs = rsqrtf(var + 1e-5f);
      if (n < NN) {
#pragma unroll
        for (int q4 = 0; q4 < 4; ++q4) {
          const int j = ln + (q4 << 6);
          comb[(size_t)n * 512 + 256 + j] = f2b((pre[q4] - mu) * rs * gmeta[j] + bmeta[j]);
        }
      }
    }
  }
}

// ---------------------------------------------------------------------------
// final: out = LN(x + combined) * g + b; combined == out (in-place safe:
// all reads of the row happen before any write, separated by __syncthreads)
// ---------------------------------------------------------------------------
__global__ void final_k(const float* __restrict__ x, const float* __restrict__ combined,
                        const float* __restrict__ g, const float* __restrict__ b,
                        float* __restrict__ out)
{
  __shared__ float sred[8];
  const int n = blockIdx.x, t = threadIdx.x;
  const float v = x[(size_t)n * HH + t] + combined[(size_t)n * HH + t];
  float s = v, s2 = v * v;
#pragma unroll
  for (int off = 32; off > 0; off >>= 1) { s += __shfl_down(s, off, 64); s2 += __shfl_down(s2, off, 64); }
  const int wv = t >> 6;
  if ((t & 63) == 0) { sred[wv] = s; sred[4 + wv] = s2; }
  __syncthreads();
  const float st = sred[0] + sred[1] + sred[2] + sred[3];
  const float st2 = sred[4] + sred[5] + sred[6] + sred[7];
  const float mu = st * (1.0f / 256.0f);
  const float var = st2 * (1.0f / 256.0f) - mu * mu;
  const float rs = rsqrtf(var + 1e-5f);
  out[(size_t)n * HH + t] = (v - mu) * rs * g[t] + b[t];
}

// ---------------------------------------------------------------------------
extern "C" void kernel_launch(void* const* d_in, const int* in_sizes, int n_in,
                              void* d_out, int out_size, void* d_ws, size_t ws_size,
                              hipStream_t stream)
{
  const float* x      = (const float*)d_in[0];
  const int*   eidx   = (const int*)d_in[1];
  const float* eattr  = (const float*)d_in[2];
  const float* Wq     = (const float*)d_in[3];
  const float* bq     = (const float*)d_in[4];
  const float* Wk     = (const float*)d_in[5];
  const float* bk     = (const float*)d_in[6];
  const float* Wv     = (const float*)d_in[7];
  const float* bv     = (const float*)d_in[8];
  const float* prior  = (const float*)d_in[9];
  const float* Wm     = (const float*)d_in[10];
  const float* bm     = (const float*)d_in[11];
  const float* W_ir1  = (const float*)d_in[12];
  const float* b_ir1  = (const float*)d_in[13];
  const float* W_ir2  = (const float*)d_in[14];
  const float* b_ir2  = (const float*)d_in[15];
  const float* Wmp    = (const float*)d_in[16];
  const float* bmp    = (const float*)d_in[17];
  const float* Wa1    = (const float*)d_in[18];
  const float* ba1    = (const float*)d_in[19];
  const float* Wa2    = (const float*)d_in[20];
  const float* g_meta = (const float*)d_in[21];
  const float* b_meta = (const float*)d_in[22];
  const float* Wc     = (const float*)d_in[23];
  const float* bc     = (const float*)d_in[24];
  const float* g_out  = (const float*)d_in[25];
  const float* b_out  = (const float*)d_in[26];
  float* out = (float*)d_out;

  // ---- workspace layout: peak = 153,600,000 + 82,277,376 = 235,877,376 B ----
  char* ws = (char*)d_ws;
  bf16* rel = (bf16*)ws;                          // [RR][NN][HH] bf16 = 153,600,000
  char* arena = ws + 153600000;
  // phase-1 views (reused across relations); agg lives in d_out (fp32, 51.2MB)
  bf16*     q     = (bf16*)(arena + 0);            // 25,600,000
  bf16*     kvb   = (bf16*)(arena + 25600000);     // 17,825,792
  bf16*     kbuf  = (bf16*)(arena + 43425792);     // 16,777,216
  bf16*     vbuf  = (bf16*)(arena + 60203008);     // 16,777,216
  float*    sc    = (float*)(arena + 76980224);    //  1,048,576
  float*    exb   = (float*)(arena + 78028800);    //  1,048,576
  unsigned* mkey  = (unsigned*)(arena + 79077376); //  1,600,000
  float*    denom = (float*)(arena + 80677376);    //  1,600,000  (arena end 82,277,376)
  float*    agg   = out;                           // d_out reused as fp32 accumulator
  // phase-2+ overlay of the same arena
  bf16*  hbuf     = (bf16*)(arena + 0);            // 25,600,000
  float* interw   = (float*)(arena + 25600000);    //  1,200,000
  bf16*  comb     = (bf16*)(arena + 26800000);     // 51,200,000 (end 78,000,000)
  float* combined = out;                           // d_out reused again in phase 4

  const dim3 gN(782, 4);   // M=50000 row blocks x 4 col blocks (NC=256)
  const dim3 gE(512, 4);   // M=32768

  // ---- phase 1: per-relation attention ----
  for (int r = 0; r < RR; ++r) {
    const int* src = eidx + (size_t)r * 2 * EE;
    const int* dst = src + EE;
    zero_k<<<256, 256, 0, stream>>>((uint4*)mkey, (NN * NHEAD * 4) / 16);
    zero_k<<<256, 256, 0, stream>>>((uint4*)denom, (NN * NHEAD * 4) / 16);
    zero_k<<<2048, 256, 0, stream>>>((uint4*)agg, (NN * HH * 4) / 16);
    gather_kv<<<EE, 256, 0, stream>>>(x, src, eattr + (size_t)r * EE * FF, kvb);
    gemm_k<float, bf16, 0, false><<<gN, 256, 0, stream>>>(
        x, Wq + (size_t)r * HH * HH, bq + r * HH, q, NN, HH, HH);
    gemm_k<bf16, bf16, 0, false><<<gE, 256, 0, stream>>>(
        kvb, Wk + (size_t)r * KV_K * HH, bk + r * HH, kbuf, EE, KV_K, HH);
    gemm_k<bf16, bf16, 0, false><<<gE, 256, 0, stream>>>(
        kvb, Wv + (size_t)r * KV_K * HH, bv + r * HH, vbuf, EE, KV_K, HH);
    scores_k<<<EE, 256, 0, stream>>>(q, kbuf, dst, prior + r * NHEAD, sc, mkey);
    expden_k<<<(EE * NHEAD + 255) / 256, 256, 0, stream>>>(sc, dst, mkey, exb, denom);
    agg_k<<<EE, 256, 0, stream>>>(exb, denom, vbuf, dst, agg);
    gemm_k<float, bf16, 1, false><<<gN, 256, 0, stream>>>(
        agg, Wm + (size_t)r * HH * HH, bm + r * HH, rel + (size_t)r * NN * HH, NN, HH, HH);
  }

  // ---- phase 2: inter-relation mixing ----
  gemm_k<bf16, bf16, 1, true><<<gN, 256, 0, stream>>>(
      rel, W_ir1, b_ir1, hbuf, NN, RR * HH, HH);
  interw_k<<<NN / 4, 256, 0, stream>>>(hbuf, W_ir2, b_ir2, interw);
  interagg_k<<<NN, 256, 0, stream>>>(interw, rel, comb);

  // ---- phase 3: fused meta-path attention + LN ----
  meta_k<<<NN / MG, 256, 0, stream>>>(rel, Wmp, bmp, Wa1, ba1, Wa2, g_meta, b_meta, comb);

  // ---- phase 4: combine + output LN (in d_out) ----
  gemm_k<bf16, float, 1, false><<<gN, 256, 0, stream>>>(
      comb, Wc, bc, combined, NN, 512, HH);
  final_k<<<NN, 256, 0, stream>>>(x, combined, g_out, b_out, out);
}

// Round 4
// 1828.604 us; speedup vs baseline: 2.6080x; 2.6080x over previous
//
#include <hip/hip_runtime.h>
#include <hip/hip_bf16.h>

typedef __hip_bfloat16 bf16;
typedef __attribute__((ext_vector_type(8))) short short8;
typedef __attribute__((ext_vector_type(4))) float f32x4;

#define NN 50000
#define RR 6
#define EE 32768
#define HH 256
#define FF 16
#define NHEAD 8
#define KVP 288   // 272 padded to multiple of 32

struct __align__(8) bf16x4 { bf16 v[4]; };

__device__ __forceinline__ float b2f(bf16 v) { return __bfloat162float(v); }
__device__ __forceinline__ bf16 f2b(float v) { return __float2bfloat16(v); }
__device__ __forceinline__ short f2s(float f) { bf16 b = f2b(f); return __builtin_bit_cast(short, b); }
__device__ __forceinline__ float s2f(short s) { return b2f(__builtin_bit_cast(bf16, s)); }
__device__ __forceinline__ float gelu_f(float x) { return 0.5f * x * (1.0f + erff(x * 0.7071067811865476f)); }
__device__ __forceinline__ unsigned fkey(float f) { unsigned u = __float_as_uint(f); return (u & 0x80000000u) ? ~u : (u | 0x80000000u); }
__device__ __forceinline__ float fdec(unsigned k) { unsigned u = (k & 0x80000000u) ? (k & 0x7fffffffu) : ~k; return __uint_as_float(u); }

// async global->LDS, 16B per lane (dest = wave-uniform base + lane*16)
__device__ __forceinline__ void gl2lds16(const void* g, void* l) {
  __builtin_amdgcn_global_load_lds(
      (const __attribute__((address_space(1))) unsigned int*)g,
      (__attribute__((address_space(3))) unsigned int*)l, 16, 0, 0);
}

// grid-stride zero fill (16B granules)
__global__ void zero_k(uint4* __restrict__ p, int n16)
{
  const uint4 z = make_uint4(0u, 0u, 0u, 0u);
  for (int i = blockIdx.x * blockDim.x + threadIdx.x; i < n16; i += gridDim.x * blockDim.x)
    p[i] = z;
}

// transpose-convert: in fp32 [K][NC] -> out bf16 [NC][Kp], zero-pad K..Kp. batch via z.
__global__ void tconv_k(const float* __restrict__ in, bf16* __restrict__ out,
                        int K, int NC, int Kp)
{
  __shared__ float t[32][33];
  in  += (size_t)blockIdx.z * K * NC;
  out += (size_t)blockIdx.z * NC * Kp;
  const int kb = blockIdx.x * 32, nb = blockIdx.y * 32;
  const int tx = threadIdx.x & 31, ty = threadIdx.x >> 5;  // ty 0..7
  for (int i = ty; i < 32; i += 8) {
    const int k = kb + i, n = nb + tx;
    t[i][tx] = (k < K && n < NC) ? in[(size_t)k * NC + n] : 0.f;
  }
  __syncthreads();
  for (int i = ty; i < 32; i += 8) {
    const int n = nb + i, k = kb + tx;
    if (n < NC && k < Kp) out[(size_t)n * Kp + k] = f2b(t[tx][i]);
  }
}

// copy tmp [N][256] bf16 -> rel_cat slot (ld 1536)
__global__ void copyslot_k(const bf16* __restrict__ tmp, bf16* __restrict__ slot)
{
  const int i = blockIdx.x * 256 + threadIdx.x;  // 8-elem chunk id
  if (i >= NN * 32) return;
  const int n = i >> 5, c = (i & 31) * 8;
  *(short8*)(slot + (size_t)n * 1536 + c) = *(const short8*)(tmp + (size_t)n * 256 + c);
}

// ---------------------------------------------------------------------------
// MFMA GEMM: C[M,NC] = act(A[M,K] @ Bt^T + bias), Bt = [NC][K] bf16 k-contig.
// 128x128 tile, BK=32, 4 waves, each wave 64x64 (4x4 of 16x16x32 MFMA).
// ASRC: 0=A bf16 (async gl2lds16); 1=A fp32, convert in staging;
//       2=PAIR: A,A2 bf16, element sum; 3=KV gather: A=x fp32 via src + eattr + pad.
// LOGITS: epilogue atomicAdd(logits[row], sum_col tanh(c+bias[col])*wa2[col]).
// ---------------------------------------------------------------------------
template<int ASRC, int ACT, bool LOGITS, typename TO>
__global__ __launch_bounds__(256) void mm_k(
    const void* __restrict__ Av, const bf16* __restrict__ A2, int lda,
    const int* __restrict__ src, const float* __restrict__ eattr,
    const bf16* __restrict__ Bt, const float* __restrict__ bias,
    const float* __restrict__ wa2, TO* __restrict__ C, int ldc,
    float* __restrict__ logits, int M, int K)
{
  __shared__ short lA[128 * 32];
  __shared__ short lB[128 * 32];
  const int tid = threadIdx.x;
  const int w = tid >> 6, l = tid & 63;
  const int row0 = blockIdx.x << 7;
  const int col0 = blockIdx.y << 7;
  const int wm = (w >> 1) << 6, wn = (w & 1) << 6;
  const int lane15 = l & 15, kq = l >> 4;

  f32x4 acc[4][4] = {};

  for (int k0 = 0; k0 < K; k0 += 32) {
    // stage A tile [128][32]
#pragma unroll
    for (int i = 0; i < 2; ++i) {
      const int idx = (w * 2 + i) * 64 + l;        // 0..511 16B chunks
      const int row = idx >> 2, cg = idx & 3;
      const int r = min(row0 + row, M - 1);
      const int kc = k0 + cg * 8;
      if constexpr (ASRC == 0) {
        gl2lds16((const bf16*)Av + (size_t)r * lda + kc, &lA[idx * 8]);
      } else if constexpr (ASRC == 1) {
        const float* p = (const float*)Av + (size_t)r * lda + kc;
        const float4 f0 = *(const float4*)p;
        const float4 f1 = *(const float4*)(p + 4);
        short8 s;
        s[0] = f2s(f0.x); s[1] = f2s(f0.y); s[2] = f2s(f0.z); s[3] = f2s(f0.w);
        s[4] = f2s(f1.x); s[5] = f2s(f1.y); s[6] = f2s(f1.z); s[7] = f2s(f1.w);
        *(short8*)&lA[idx * 8] = s;
      } else if constexpr (ASRC == 2) {
        const short8 u = *(const short8*)((const bf16*)Av + (size_t)r * lda + kc);
        const short8 v2 = *(const short8*)(A2 + (size_t)r * lda + kc);
        short8 s;
#pragma unroll
        for (int j = 0; j < 8; ++j) s[j] = f2s(s2f(u[j]) + s2f(v2[j]));
        *(short8*)&lA[idx * 8] = s;
      } else {  // ASRC == 3: kv gather
        short8 s;
        if (kc < HH) {
          const float* p = (const float*)Av + (size_t)src[r] * HH + kc;
          const float4 f0 = *(const float4*)p;
          const float4 f1 = *(const float4*)(p + 4);
          s[0] = f2s(f0.x); s[1] = f2s(f0.y); s[2] = f2s(f0.z); s[3] = f2s(f0.w);
          s[4] = f2s(f1.x); s[5] = f2s(f1.y); s[6] = f2s(f1.z); s[7] = f2s(f1.w);
        } else if (kc < HH + FF) {
          const float* p = eattr + (size_t)r * FF + (kc - HH);
          const float4 f0 = *(const float4*)p;
          const float4 f1 = *(const float4*)(p + 4);
          s[0] = f2s(f0.x); s[1] = f2s(f0.y); s[2] = f2s(f0.z); s[3] = f2s(f0.w);
          s[4] = f2s(f1.x); s[5] = f2s(f1.y); s[6] = f2s(f1.z); s[7] = f2s(f1.w);
        } else {
#pragma unroll
          for (int j = 0; j < 8; ++j) s[j] = 0;
        }
        *(short8*)&lA[idx * 8] = s;
      }
    }
    // stage B tile [128][32] (block's 128 cols always in range)
#pragma unroll
    for (int i = 0; i < 2; ++i) {
      const int idx = (w * 2 + i) * 64 + l;
      const int row = idx >> 2, cg = idx & 3;
      gl2lds16(Bt + (size_t)(col0 + row) * K + k0 + cg * 8, &lB[idx * 8]);
    }
    __syncthreads();
    short8 af[4], bfr[4];
#pragma unroll
    for (int t = 0; t < 4; ++t) {
      af[t]  = *(const short8*)&lA[(wm + t * 16 + lane15) * 32 + kq * 8];
      bfr[t] = *(const short8*)&lB[(wn + t * 16 + lane15) * 32 + kq * 8];
    }
#pragma unroll
    for (int ti = 0; ti < 4; ++ti)
#pragma unroll
      for (int tj = 0; tj < 4; ++tj)
        acc[ti][tj] = __builtin_amdgcn_mfma_f32_16x16x32_bf16(af[ti], bfr[tj], acc[ti][tj], 0, 0, 0);
    __syncthreads();
  }

  if constexpr (!LOGITS) {
    // C layout: col = lane&15, row = (lane>>4)*4 + reg  [m89-verified]
#pragma unroll
    for (int ti = 0; ti < 4; ++ti) {
#pragma unroll
      for (int reg = 0; reg < 4; ++reg) {
        const int row = row0 + wm + ti * 16 + kq * 4 + reg;
        if (row >= M) continue;
#pragma unroll
        for (int tj = 0; tj < 4; ++tj) {
          const int col = col0 + wn + tj * 16 + lane15;
          float v = acc[ti][tj][reg] + bias[col];
          if constexpr (ACT == 1) v = gelu_f(v);
          if constexpr (sizeof(TO) == 2) C[(size_t)row * ldc + col] = (TO)f2b(v);
          else                           C[(size_t)row * ldc + col] = (TO)v;
        }
      }
    }
  } else {
#pragma unroll
    for (int ti = 0; ti < 4; ++ti) {
#pragma unroll
      for (int reg = 0; reg < 4; ++reg) {
        float part = 0.f;
#pragma unroll
        for (int tj = 0; tj < 4; ++tj) {
          const int col = col0 + wn + tj * 16 + lane15;
          part += tanhf(acc[ti][tj][reg] + bias[col]) * wa2[col];
        }
#pragma unroll
        for (int off = 8; off > 0; off >>= 1) part += __shfl_xor(part, off, 64);
        const int row = row0 + wm + ti * 16 + kq * 4 + reg;
        if (lane15 == 0 && row < M) atomicAdd(&logits[row], part);
      }
    }
  }
}

// ---------------------------------------------------------------------------
// Edge-side kernels
// ---------------------------------------------------------------------------
__global__ void scores_k(const bf16* __restrict__ q, const bf16* __restrict__ k,
                         const int* __restrict__ dst_idx, const float* __restrict__ prior_r,
                         float* __restrict__ scores, unsigned* __restrict__ mkey)
{
  const int e = blockIdx.x, t = threadIdx.x;
  const int dst = dst_idx[e];
  float p = b2f(q[(size_t)dst * HH + t]) * b2f(k[(size_t)e * HH + t]);
#pragma unroll
  for (int off = 16; off > 0; off >>= 1) p += __shfl_down(p, off, 32);
  const int h = t >> 5;
  if ((t & 31) == 0) {
    const float s = p * 0.1767766952966369f * prior_r[h];
    scores[e * NHEAD + h] = s;
    atomicMax(&mkey[dst * NHEAD + h], fkey(s));
  }
}

__global__ void expden_k(const float* __restrict__ scores, const int* __restrict__ dst_idx,
                         const unsigned* __restrict__ mkey, float* __restrict__ ex,
                         float* __restrict__ denom)
{
  const int idx = blockIdx.x * 256 + threadIdx.x;
  if (idx >= EE * NHEAD) return;
  const int e = idx >> 3, h = idx & 7;
  const int dst = dst_idx[e];
  const float m = fdec(mkey[dst * NHEAD + h]);
  const float v = expf(scores[idx] - m);
  ex[idx] = v;
  atomicAdd(&denom[dst * NHEAD + h], v);
}

__global__ void agg_k(const float* __restrict__ ex, const float* __restrict__ denom,
                      const bf16* __restrict__ v, const int* __restrict__ dst_idx,
                      float* __restrict__ agg)
{
  const int e = blockIdx.x, t = threadIdx.x, h = t >> 5;
  const int dst = dst_idx[e];
  const float w = ex[e * NHEAD + h] / (denom[dst * NHEAD + h] + 1e-16f);
  atomicAdd(&agg[(size_t)dst * HH + t], w * b2f(v[(size_t)e * HH + t]));
}

// ---------------------------------------------------------------------------
// inter-relation softmax weights; one wave per node
// ---------------------------------------------------------------------------
__global__ void interw_k(const bf16* __restrict__ h, const float* __restrict__ W2,
                         const float* __restrict__ b2, float* __restrict__ interw)
{
  const int wv = threadIdx.x >> 6, ln = threadIdx.x & 63;
  const int n = blockIdx.x * 4 + wv;
  if (n >= NN) return;
  float a[6] = {0.f, 0.f, 0.f, 0.f, 0.f, 0.f};
#pragma unroll
  for (int kq = 0; kq < 4; ++kq) {
    const int k = ln + (kq << 6);
    const float hv = b2f(h[(size_t)n * HH + k]);
#pragma unroll
    for (int j = 0; j < 6; ++j) a[j] += hv * W2[k * 6 + j];
  }
#pragma unroll
  for (int j = 0; j < 6; ++j) {
#pragma unroll
    for (int off = 32; off > 0; off >>= 1) a[j] += __shfl_down(a[j], off, 64);
  }
  if (ln == 0) {
    float lg[6], e[6], mx = -1e30f, s = 0.f;
#pragma unroll
    for (int j = 0; j < 6; ++j) { lg[j] = a[j] + b2[j]; mx = fmaxf(mx, lg[j]); }
#pragma unroll
    for (int j = 0; j < 6; ++j) { e[j] = expf(lg[j] - mx); s += e[j]; }
    const float inv = 1.0f / s;
#pragma unroll
    for (int j = 0; j < 6; ++j) interw[(size_t)n * 6 + j] = e[j] * inv;
  }
}

// rel_cat layout: [N][R*256]
__global__ void interagg_k(const float* __restrict__ interw, const bf16* __restrict__ rel_cat,
                           bf16* __restrict__ comb)
{
  const int n = blockIdx.x, t = threadIdx.x;
  float acc = 0.f;
#pragma unroll
  for (int r = 0; r < 6; ++r)
    acc += interw[(size_t)n * 6 + r] * b2f(rel_cat[(size_t)n * 1536 + r * 256 + t]);
  comb[(size_t)n * 512 + t] = f2b(acc);
}

// ---------------------------------------------------------------------------
// meta final: softmax(logits[3]) -> weighted sum of stacked -> LN -> comb[:,256:]
// stacked[p] lives in rel_cat slots {2,4,1} (ld 1536); logits = [3][N] fp32
// ---------------------------------------------------------------------------
__global__ void metafinal_k(const float* __restrict__ logits, const bf16* __restrict__ rel_cat,
                            const float* __restrict__ gmeta, const float* __restrict__ bmeta,
                            bf16* __restrict__ comb)
{
  const int wv = threadIdx.x >> 6, ln = threadIdx.x & 63;
  const int n = blockIdx.x * 4 + wv;
  if (n >= NN) return;
  const float l0 = logits[n], l1 = logits[NN + n], l2 = logits[2 * NN + n];
  const float mx = fmaxf(l0, fmaxf(l1, l2));
  const float e0 = expf(l0 - mx), e1 = expf(l1 - mx), e2 = expf(l2 - mx);
  const float inv = 1.0f / (e0 + e1 + e2);
  const float a0 = e0 * inv, a1 = e1 * inv, a2 = e2 * inv;
  const size_t base = (size_t)n * 1536;
  float pre[4], s = 0.f, s2 = 0.f;
#pragma unroll
  for (int q4 = 0; q4 < 4; ++q4) {
    const int j = ln + (q4 << 6);
    const float v = a0 * b2f(rel_cat[base + 2 * 256 + j])
                  + a1 * b2f(rel_cat[base + 4 * 256 + j])
                  + a2 * b2f(rel_cat[base + 1 * 256 + j]);
    pre[q4] = v; s += v; s2 += v * v;
  }
#pragma unroll
  for (int off = 32; off > 0; off >>= 1) { s += __shfl_down(s, off, 64); s2 += __shfl_down(s2, off, 64); }
  s = __shfl(s, 0, 64); s2 = __shfl(s2, 0, 64);
  const float mu = s * (1.0f / 256.0f);
  const float var = s2 * (1.0f / 256.0f) - mu * mu;
  const float rs = rsqrtf(var + 1e-5f);
#pragma unroll
  for (int q4 = 0; q4 < 4; ++q4) {
    const int j = ln + (q4 << 6);
    comb[(size_t)n * 512 + 256 + j] = f2b((pre[q4] - mu) * rs * gmeta[j] + bmeta[j]);
  }
}

// final: out = LN(x + combined)
__global__ void final_k(const float* __restrict__ x, const float* __restrict__ combined,
                        const float* __restrict__ g, const float* __restrict__ b,
                        float* __restrict__ out)
{
  __shared__ float sred[8];
  const int n = blockIdx.x, t = threadIdx.x;
  const float v = x[(size_t)n * HH + t] + combined[(size_t)n * HH + t];
  float s = v, s2 = v * v;
#pragma unroll
  for (int off = 32; off > 0; off >>= 1) { s += __shfl_down(s, off, 64); s2 += __shfl_down(s2, off, 64); }
  const int wv = t >> 6;
  if ((t & 63) == 0) { sred[wv] = s; sred[4 + wv] = s2; }
  __syncthreads();
  const float st = sred[0] + sred[1] + sred[2] + sred[3];
  const float st2 = sred[4] + sred[5] + sred[6] + sred[7];
  const float mu = st * (1.0f / 256.0f);
  const float var = st2 * (1.0f / 256.0f) - mu * mu;
  const float rs = rsqrtf(var + 1e-5f);
  out[(size_t)n * HH + t] = (v - mu) * rs * g[t] + b[t];
}

// ---------------------------------------------------------------------------
extern "C" void kernel_launch(void* const* d_in, const int* in_sizes, int n_in,
                              void* d_out, int out_size, void* d_ws, size_t ws_size,
                              hipStream_t stream)
{
  const float* x      = (const float*)d_in[0];
  const int*   eidx   = (const int*)d_in[1];
  const float* eattr  = (const float*)d_in[2];
  const float* Wq     = (const float*)d_in[3];
  const float* bq     = (const float*)d_in[4];
  const float* Wk     = (const float*)d_in[5];
  const float* bk     = (const float*)d_in[6];
  const float* Wv     = (const float*)d_in[7];
  const float* bv     = (const float*)d_in[8];
  const float* prior  = (const float*)d_in[9];
  const float* Wm     = (const float*)d_in[10];
  const float* bm     = (const float*)d_in[11];
  const float* W_ir1  = (const float*)d_in[12];
  const float* b_ir1  = (const float*)d_in[13];
  const float* W_ir2  = (const float*)d_in[14];
  const float* b_ir2  = (const float*)d_in[15];
  const float* Wmp    = (const float*)d_in[16];
  const float* bmp    = (const float*)d_in[17];
  const float* Wa1    = (const float*)d_in[18];
  const float* ba1    = (const float*)d_in[19];
  const float* Wa2    = (const float*)d_in[20];
  const float* g_meta = (const float*)d_in[21];
  const float* b_meta = (const float*)d_in[22];
  const float* Wc     = (const float*)d_in[23];
  const float* bc     = (const float*)d_in[24];
  const float* g_out  = (const float*)d_in[25];
  const float* b_out  = (const float*)d_in[26];
  float* out = (float*)d_out;

  // ---- workspace layout: TOTAL 222,901,248 B (< 235.88 MB proven safe) ----
  char* ws = (char*)d_ws;
  bf16* rel_cat = (bf16*)ws;                         // [N][1536] bf16 = 153,600,000
  char* W0 = ws + 153600000;                         // weights: 4,849,664
  bf16* Wqt   = (bf16*)(W0 + 0);          // [6][256][256]
  bf16* Wkt   = (bf16*)(W0 + 786432);     // [6][256][288]
  bf16* Wvt   = (bf16*)(W0 + 1671168);    // [6][256][288]
  bf16* Wmt   = (bf16*)(W0 + 2555904);    // [6][256][256]
  bf16* Wir1t = (bf16*)(W0 + 3342336);    // [256][1536]
  bf16* Wct   = (bf16*)(W0 + 4128768);    // [256][512]
  bf16* Wmpt  = (bf16*)(W0 + 4390912);    // [3][256][256]
  bf16* Wa1t  = (bf16*)(W0 + 4784128);    // [128][256] (end 4,849,664)
  char* region = ws + 158449664;                     // 64,451,584 B
  // phase-1 views
  bf16*     q     = (bf16*)(region + 0);             // 25,600,000
  bf16*     kbuf  = (bf16*)(region + 25600000);      // 16,777,216
  bf16*     vbuf  = (bf16*)(region + 42377216);      // 16,777,216
  float*    sc    = (float*)(region + 59154432);     //  1,048,576
  float*    exb   = (float*)(region + 60203008);     //  1,048,576
  unsigned* mkey  = (unsigned*)(region + 61251584);  //  1,600,000
  float*    denom = (float*)(region + 62851584);     //  1,600,000 (end 64,451,584)
  float*    agg   = out;                             // d_out as fp32 accumulator (phase 1)
  // phase-4 overlay
  bf16*  hbuf     = (bf16*)(region + 25600000);      // 25,600,000 (kbuf/vbuf slots)
  float* interw   = (float*)(region + 59154432);     //  1,200,000 (sc/exb slots)
  // phase-3 overlay
  bf16*  tmp      = (bf16*)(region + 25600000);      // 25,600,000 (after hbuf dead)
  float* logits   = (float*)(region + 61251584);     //    600,000 (mkey slot)
  // phase-5
  bf16*  comb     = (bf16*)out;                      // [N][512] bf16 in d_out
  float* combined = (float*)(region + 0);            // [N][256] fp32 (phase-1 slots dead)

  const dim3 gN(391, 2);    // M=50000, NC=256
  const dim3 gE(256, 2);    // M=32768, NC=256
  const dim3 gL(391, 1);    // M=50000, NC=128 (logits)

  // ---- phase 0: weight transpose/convert ----
  tconv_k<<<dim3(8, 8, 6), 256, 0, stream>>>(Wq, Wqt, 256, 256, 256);
  tconv_k<<<dim3(9, 8, 6), 256, 0, stream>>>(Wk, Wkt, 272, 256, 288);
  tconv_k<<<dim3(9, 8, 6), 256, 0, stream>>>(Wv, Wvt, 272, 256, 288);
  tconv_k<<<dim3(8, 8, 6), 256, 0, stream>>>(Wm, Wmt, 256, 256, 256);
  tconv_k<<<dim3(48, 8, 1), 256, 0, stream>>>(W_ir1, Wir1t, 1536, 256, 1536);
  tconv_k<<<dim3(16, 8, 1), 256, 0, stream>>>(Wc, Wct, 512, 256, 512);
  tconv_k<<<dim3(8, 8, 3), 256, 0, stream>>>(Wmp, Wmpt, 256, 256, 256);
  tconv_k<<<dim3(8, 4, 1), 256, 0, stream>>>(Wa1, Wa1t, 256, 128, 256);

  // ---- phase 1: per-relation attention ----
  for (int r = 0; r < RR; ++r) {
    const int* src = eidx + (size_t)r * 2 * EE;
    const int* dst = src + EE;
    const float* ea = eattr + (size_t)r * EE * FF;
    zero_k<<<256, 256, 0, stream>>>((uint4*)mkey, (NN * NHEAD * 4) / 16);
    zero_k<<<256, 256, 0, stream>>>((uint4*)denom, (NN * NHEAD * 4) / 16);
    zero_k<<<2048, 256, 0, stream>>>((uint4*)agg, (NN * HH * 4) / 16);
    // q = x @ Wq[r] + bq[r]   (fp32 A, convert in staging)
    mm_k<1, 0, false, bf16><<<gN, 256, 0, stream>>>(
        x, nullptr, 256, nullptr, nullptr,
        Wqt + (size_t)r * 256 * 256, bq + r * HH, nullptr, q, 256, nullptr, NN, 256);
    // k/v = [x[src]||eattr||0] @ Wk/Wv  (gather in staging)
    mm_k<3, 0, false, bf16><<<gE, 256, 0, stream>>>(
        x, nullptr, 0, src, ea,
        Wkt + (size_t)r * 256 * KVP, bk + r * HH, nullptr, kbuf, 256, nullptr, EE, KVP);
    mm_k<3, 0, false, bf16><<<gE, 256, 0, stream>>>(
        x, nullptr, 0, src, ea,
        Wvt + (size_t)r * 256 * KVP, bv + r * HH, nullptr, vbuf, 256, nullptr, EE, KVP);
    scores_k<<<EE, 256, 0, stream>>>(q, kbuf, dst, prior + r * NHEAD, sc, mkey);
    expden_k<<<(EE * NHEAD + 255) / 256, 256, 0, stream>>>(sc, dst, mkey, exb, denom);
    agg_k<<<EE, 256, 0, stream>>>(exb, denom, vbuf, dst, agg);
    // rel[r] = gelu(agg @ Wm[r] + bm[r]) -> rel_cat slot r (fp32 A)
    mm_k<1, 1, false, bf16><<<gN, 256, 0, stream>>>(
        agg, nullptr, 256, nullptr, nullptr,
        Wmt + (size_t)r * 256 * 256, bm + r * HH, nullptr,
        rel_cat + r * 256, 1536, nullptr, NN, 256);
  }

  // ---- phase 2: inter-relation chain (consumes rel_cat BEFORE meta overwrites) ----
  mm_k<0, 1, false, bf16><<<gN, 256, 0, stream>>>(
      rel_cat, nullptr, 1536, nullptr, nullptr,
      Wir1t, b_ir1, nullptr, hbuf, 256, nullptr, NN, 1536);
  interw_k<<<(NN + 3) / 4, 256, 0, stream>>>(hbuf, W_ir2, b_ir2, interw);
  interagg_k<<<NN, 256, 0, stream>>>(interw, rel_cat, comb);

  // ---- phase 3: meta-path chain (in-place into rel_cat slots {2,4,1}) ----
  const int r1[3] = {2, 4, 1};
  const int r2[3] = {3, 0, 5};
  zero_k<<<147, 256, 0, stream>>>((uint4*)logits, (3 * NN * 4) / 16);
  for (int p = 0; p < 3; ++p) {
    // tmp = (rel[r1]+rel[r2]) @ Wmp[p] + bmp[p]
    mm_k<2, 0, false, bf16><<<gN, 256, 0, stream>>>(
        rel_cat + r1[p] * 256, rel_cat + r2[p] * 256, 1536, nullptr, nullptr,
        Wmpt + (size_t)p * 256 * 256, bmp + p * 256, nullptr, tmp, 256, nullptr, NN, 256);
    // logits[p] = sum_i tanh(tmp @ Wa1 + ba1)_i * Wa2_i
    mm_k<0, 0, true, bf16><<<gL, 256, 0, stream>>>(
        tmp, nullptr, 256, nullptr, nullptr,
        Wa1t, ba1, Wa2, (bf16*)nullptr, 0, logits + (size_t)p * NN, NN, 256);
    // write stacked[p] back into (now dead) rel_cat slot r1[p]
    copyslot_k<<<(NN * 32 + 255) / 256, 256, 0, stream>>>(tmp, rel_cat + r1[p] * 256);
  }
  metafinal_k<<<(NN + 3) / 4, 256, 0, stream>>>(logits, rel_cat, g_meta, b_meta, comb);

  // ---- phase 4: combine + output LN (d_out) ----
  mm_k<0, 1, false, float><<<gN, 256, 0, stream>>>(
      comb, nullptr, 512, nullptr, nullptr,
      Wct, bc, nullptr, combined, 256, nullptr, NN, 512);
  final_k<<<NN, 256, 0, stream>>>(x, combined, g_out, b_out, out);
}

// Round 5
// 1777.867 us; speedup vs baseline: 2.6824x; 1.0285x over previous
//
#include <hip/hip_runtime.h>
#include <hip/hip_bf16.h>

typedef __hip_bfloat16 bf16;
typedef __attribute__((ext_vector_type(8))) short short8;
typedef __attribute__((ext_vector_type(4))) float f32x4;

#define NN 50000
#define RR 6
#define EE 32768
#define HH 256
#define FF 16
#define NHEAD 8
#define KVP 288   // 272 padded to multiple of 32

struct __align__(8) bf16x4 { bf16 v[4]; };

__device__ __forceinline__ float b2f(bf16 v) { return __bfloat162float(v); }
__device__ __forceinline__ bf16 f2b(float v) { return __float2bfloat16(v); }
__device__ __forceinline__ short f2s(float f) { bf16 b = f2b(f); return __builtin_bit_cast(short, b); }
__device__ __forceinline__ float s2f(short s) { return b2f(__builtin_bit_cast(bf16, s)); }
__device__ __forceinline__ float gelu_f(float x) { return 0.5f * x * (1.0f + erff(x * 0.7071067811865476f)); }
__device__ __forceinline__ unsigned fkey(float f) { unsigned u = __float_as_uint(f); return (u & 0x80000000u) ? ~u : (u | 0x80000000u); }
__device__ __forceinline__ float fdec(unsigned k) { unsigned u = (k & 0x80000000u) ? (k & 0x7fffffffu) : ~k; return __uint_as_float(u); }

// async global->LDS, 16B per lane (dest = wave-uniform base + lane*16)
__device__ __forceinline__ void gl2lds16(const void* g, void* l) {
  __builtin_amdgcn_global_load_lds(
      (const __attribute__((address_space(1))) unsigned int*)g,
      (__attribute__((address_space(3))) unsigned int*)l, 16, 0, 0);
}

// grid-stride zero fill (16B granules)
__global__ void zero_k(uint4* __restrict__ p, int n16)
{
  const uint4 z = make_uint4(0u, 0u, 0u, 0u);
  for (int i = blockIdx.x * blockDim.x + threadIdx.x; i < n16; i += gridDim.x * blockDim.x)
    p[i] = z;
}

// transpose-convert: in fp32 [K][NC] -> out bf16 [NC][Kp], zero-pad K..Kp.
// batch via z with explicit element strides (izs for in, ozs for out).
__global__ void tconv_k(const float* __restrict__ in, bf16* __restrict__ out,
                        int K, int NC, int Kp, long izs, long ozs)
{
  __shared__ float t[32][33];
  in  += (size_t)blockIdx.z * izs;
  out += (size_t)blockIdx.z * ozs;
  const int kb = blockIdx.x * 32, nb = blockIdx.y * 32;
  const int tx = threadIdx.x & 31, ty = threadIdx.x >> 5;  // ty 0..7
  for (int i = ty; i < 32; i += 8) {
    const int k = kb + i, n = nb + tx;
    t[i][tx] = (k < K && n < NC) ? in[(size_t)k * NC + n] : 0.f;
  }
  __syncthreads();
  for (int i = ty; i < 32; i += 8) {
    const int n = nb + i, k = kb + tx;
    if (n < NC && k < Kp) out[(size_t)n * Kp + k] = f2b(t[tx][i]);
  }
}

// build concatenated kv bias: bkv[r][0..255]=bk[r], bkv[r][256..511]=bv[r]
__global__ void bkv_k(const float* __restrict__ bk, const float* __restrict__ bv,
                      float* __restrict__ bkv)
{
  const int i = blockIdx.x * 256 + threadIdx.x;
  if (i >= RR * 512) return;
  const int r = i >> 9, c = i & 511;
  bkv[i] = (c < 256) ? bk[r * 256 + c] : bv[r * 256 + (c - 256)];
}

// copy tmp [N][256] bf16 -> rel_cat slot (ld 1536)
__global__ void copyslot_k(const bf16* __restrict__ tmp, bf16* __restrict__ slot)
{
  const int i = blockIdx.x * 256 + threadIdx.x;  // 8-elem chunk id
  if (i >= NN * 32) return;
  const int n = i >> 5, c = (i & 31) * 8;
  *(short8*)(slot + (size_t)n * 1536 + c) = *(const short8*)(tmp + (size_t)n * 256 + c);
}

// ---------------------------------------------------------------------------
// MFMA GEMM: C[M,NC] = act(A[M,K] @ Bt^T + bias), Bt = [NC][K] bf16 k-contig.
// 128x128 tile, BK=32, 4 waves, each wave 64x64 (4x4 of 16x16x32 MFMA).
// ASRC: 0=A bf16 (async gl2lds16); 1=A fp32, convert in staging;
//       2=PAIR: A,A2 bf16, element sum; 3=KV gather: A=x fp32 via src + eattr + pad.
// LOGITS: epilogue atomicAdd(logits[row], sum_col tanh(c+bias[col])*wa2[col]).
// ---------------------------------------------------------------------------
template<int ASRC, int ACT, bool LOGITS, typename TO>
__global__ __launch_bounds__(256) void mm_k(
    const void* __restrict__ Av, const bf16* __restrict__ A2, int lda,
    const int* __restrict__ src, const float* __restrict__ eattr,
    const bf16* __restrict__ Bt, const float* __restrict__ bias,
    const float* __restrict__ wa2, TO* __restrict__ C, int ldc,
    float* __restrict__ logits, int M, int K)
{
  __shared__ short lA[128 * 32];
  __shared__ short lB[128 * 32];
  const int tid = threadIdx.x;
  const int w = tid >> 6, l = tid & 63;
  const int row0 = blockIdx.x << 7;
  const int col0 = blockIdx.y << 7;
  const int wm = (w >> 1) << 6, wn = (w & 1) << 6;
  const int lane15 = l & 15, kq = l >> 4;

  f32x4 acc[4][4] = {};

  for (int k0 = 0; k0 < K; k0 += 32) {
    // stage A tile [128][32]
#pragma unroll
    for (int i = 0; i < 2; ++i) {
      const int idx = (w * 2 + i) * 64 + l;        // 0..511 16B chunks
      const int row = idx >> 2, cg = idx & 3;
      const int r = min(row0 + row, M - 1);
      const int kc = k0 + cg * 8;
      if constexpr (ASRC == 0) {
        gl2lds16((const bf16*)Av + (size_t)r * lda + kc, &lA[idx * 8]);
      } else if constexpr (ASRC == 1) {
        const float* p = (const float*)Av + (size_t)r * lda + kc;
        const float4 f0 = *(const float4*)p;
        const float4 f1 = *(const float4*)(p + 4);
        short8 s;
        s[0] = f2s(f0.x); s[1] = f2s(f0.y); s[2] = f2s(f0.z); s[3] = f2s(f0.w);
        s[4] = f2s(f1.x); s[5] = f2s(f1.y); s[6] = f2s(f1.z); s[7] = f2s(f1.w);
        *(short8*)&lA[idx * 8] = s;
      } else if constexpr (ASRC == 2) {
        const short8 u = *(const short8*)((const bf16*)Av + (size_t)r * lda + kc);
        const short8 v2 = *(const short8*)(A2 + (size_t)r * lda + kc);
        short8 s;
#pragma unroll
        for (int j = 0; j < 8; ++j) s[j] = f2s(s2f(u[j]) + s2f(v2[j]));
        *(short8*)&lA[idx * 8] = s;
      } else {  // ASRC == 3: kv gather
        short8 s;
        if (kc < HH) {
          const float* p = (const float*)Av + (size_t)src[r] * HH + kc;
          const float4 f0 = *(const float4*)p;
          const float4 f1 = *(const float4*)(p + 4);
          s[0] = f2s(f0.x); s[1] = f2s(f0.y); s[2] = f2s(f0.z); s[3] = f2s(f0.w);
          s[4] = f2s(f1.x); s[5] = f2s(f1.y); s[6] = f2s(f1.z); s[7] = f2s(f1.w);
        } else if (kc < HH + FF) {
          const float* p = eattr + (size_t)r * FF + (kc - HH);
          const float4 f0 = *(const float4*)p;
          const float4 f1 = *(const float4*)(p + 4);
          s[0] = f2s(f0.x); s[1] = f2s(f0.y); s[2] = f2s(f0.z); s[3] = f2s(f0.w);
          s[4] = f2s(f1.x); s[5] = f2s(f1.y); s[6] = f2s(f1.z); s[7] = f2s(f1.w);
        } else {
#pragma unroll
          for (int j = 0; j < 8; ++j) s[j] = 0;
        }
        *(short8*)&lA[idx * 8] = s;
      }
    }
    // stage B tile [128][32] (block's 128 cols always in range)
#pragma unroll
    for (int i = 0; i < 2; ++i) {
      const int idx = (w * 2 + i) * 64 + l;
      const int row = idx >> 2, cg = idx & 3;
      gl2lds16(Bt + (size_t)(col0 + row) * K + k0 + cg * 8, &lB[idx * 8]);
    }
    __syncthreads();
    short8 af[4], bfr[4];
#pragma unroll
    for (int t = 0; t < 4; ++t) {
      af[t]  = *(const short8*)&lA[(wm + t * 16 + lane15) * 32 + kq * 8];
      bfr[t] = *(const short8*)&lB[(wn + t * 16 + lane15) * 32 + kq * 8];
    }
#pragma unroll
    for (int ti = 0; ti < 4; ++ti)
#pragma unroll
      for (int tj = 0; tj < 4; ++tj)
        acc[ti][tj] = __builtin_amdgcn_mfma_f32_16x16x32_bf16(af[ti], bfr[tj], acc[ti][tj], 0, 0, 0);
    __syncthreads();
  }

  if constexpr (!LOGITS) {
    // C layout: col = lane&15, row = (lane>>4)*4 + reg  [m89-verified]
#pragma unroll
    for (int ti = 0; ti < 4; ++ti) {
#pragma unroll
      for (int reg = 0; reg < 4; ++reg) {
        const int row = row0 + wm + ti * 16 + kq * 4 + reg;
        if (row >= M) continue;
#pragma unroll
        for (int tj = 0; tj < 4; ++tj) {
          const int col = col0 + wn + tj * 16 + lane15;
          float v = acc[ti][tj][reg] + bias[col];
          if constexpr (ACT == 1) v = gelu_f(v);
          if constexpr (sizeof(TO) == 2) C[(size_t)row * ldc + col] = (TO)f2b(v);
          else                           C[(size_t)row * ldc + col] = (TO)v;
        }
      }
    }
  } else {
#pragma unroll
    for (int ti = 0; ti < 4; ++ti) {
#pragma unroll
      for (int reg = 0; reg < 4; ++reg) {
        float part = 0.f;
#pragma unroll
        for (int tj = 0; tj < 4; ++tj) {
          const int col = col0 + wn + tj * 16 + lane15;
          part += tanhf(acc[ti][tj][reg] + bias[col]) * wa2[col];
        }
#pragma unroll
        for (int off = 8; off > 0; off >>= 1) part += __shfl_xor(part, off, 64);
        const int row = row0 + wm + ti * 16 + kq * 4 + reg;
        if (lane15 == 0 && row < M) atomicAdd(&logits[row], part);
      }
    }
  }
}

// ---------------------------------------------------------------------------
// Edge-side kernels; q lives in rel_cat (ld 1536, slot r), k/v in kv [E][512]
// ---------------------------------------------------------------------------
__global__ void scores_k(const bf16* __restrict__ q, const bf16* __restrict__ kv,
                         const int* __restrict__ dst_idx, const float* __restrict__ prior_r,
                         float* __restrict__ scores, unsigned* __restrict__ mkey)
{
  const int e = blockIdx.x, t = threadIdx.x;
  const int dst = dst_idx[e];
  float p = b2f(q[(size_t)dst * 1536 + t]) * b2f(kv[(size_t)e * 512 + t]);
#pragma unroll
  for (int off = 16; off > 0; off >>= 1) p += __shfl_down(p, off, 32);
  const int h = t >> 5;
  if ((t & 31) == 0) {
    const float s = p * 0.1767766952966369f * prior_r[h];
    scores[e * NHEAD + h] = s;
    atomicMax(&mkey[dst * NHEAD + h], fkey(s));
  }
}

__global__ void expden_k(const float* __restrict__ scores, const int* __restrict__ dst_idx,
                         const unsigned* __restrict__ mkey, float* __restrict__ ex,
                         float* __restrict__ denom)
{
  const int idx = blockIdx.x * 256 + threadIdx.x;
  if (idx >= EE * NHEAD) return;
  const int e = idx >> 3, h = idx & 7;
  const int dst = dst_idx[e];
  const float m = fdec(mkey[dst * NHEAD + h]);
  const float v = expf(scores[idx] - m);
  ex[idx] = v;
  atomicAdd(&denom[dst * NHEAD + h], v);
}

__global__ void agg_k(const float* __restrict__ ex, const float* __restrict__ denom,
                      const bf16* __restrict__ kv, const int* __restrict__ dst_idx,
                      float* __restrict__ agg)
{
  const int e = blockIdx.x, t = threadIdx.x, h = t >> 5;
  const int dst = dst_idx[e];
  const float w = ex[e * NHEAD + h] / (denom[dst * NHEAD + h] + 1e-16f);
  atomicAdd(&agg[(size_t)dst * HH + t], w * b2f(kv[(size_t)e * 512 + 256 + t]));
}

// ---------------------------------------------------------------------------
// inter-relation softmax weights; one wave per node
// ---------------------------------------------------------------------------
__global__ void interw_k(const bf16* __restrict__ h, const float* __restrict__ W2,
                         const float* __restrict__ b2, float* __restrict__ interw)
{
  const int wv = threadIdx.x >> 6, ln = threadIdx.x & 63;
  const int n = blockIdx.x * 4 + wv;
  if (n >= NN) return;
  float a[6] = {0.f, 0.f, 0.f, 0.f, 0.f, 0.f};
#pragma unroll
  for (int kq = 0; kq < 4; ++kq) {
    const int k = ln + (kq << 6);
    const float hv = b2f(h[(size_t)n * HH + k]);
#pragma unroll
    for (int j = 0; j < 6; ++j) a[j] += hv * W2[k * 6 + j];
  }
#pragma unroll
  for (int j = 0; j < 6; ++j) {
#pragma unroll
    for (int off = 32; off > 0; off >>= 1) a[j] += __shfl_down(a[j], off, 64);
  }
  if (ln == 0) {
    float lg[6], e[6], mx = -1e30f, s = 0.f;
#pragma unroll
    for (int j = 0; j < 6; ++j) { lg[j] = a[j] + b2[j]; mx = fmaxf(mx, lg[j]); }
#pragma unroll
    for (int j = 0; j < 6; ++j) { e[j] = expf(lg[j] - mx); s += e[j]; }
    const float inv = 1.0f / s;
#pragma unroll
    for (int j = 0; j < 6; ++j) interw[(size_t)n * 6 + j] = e[j] * inv;
  }
}

// rel_cat layout: [N][R*256]
__global__ void interagg_k(const float* __restrict__ interw, const bf16* __restrict__ rel_cat,
                           bf16* __restrict__ comb)
{
  const int n = blockIdx.x, t = threadIdx.x;
  float acc = 0.f;
#pragma unroll
  for (int r = 0; r < 6; ++r)
    acc += interw[(size_t)n * 6 + r] * b2f(rel_cat[(size_t)n * 1536 + r * 256 + t]);
  comb[(size_t)n * 512 + t] = f2b(acc);
}

// ---------------------------------------------------------------------------
// meta final: softmax(logits[3]) -> weighted sum of stacked -> LN -> comb[:,256:]
// stacked[p] lives in rel_cat slots {2,4,1} (ld 1536); logits = [3][N] fp32
// ---------------------------------------------------------------------------
__global__ void metafinal_k(const float* __restrict__ logits, const bf16* __restrict__ rel_cat,
                            const float* __restrict__ gmeta, const float* __restrict__ bmeta,
                            bf16* __restrict__ comb)
{
  const int wv = threadIdx.x >> 6, ln = threadIdx.x & 63;
  const int n = blockIdx.x * 4 + wv;
  if (n >= NN) return;
  const float l0 = logits[n], l1 = logits[NN + n], l2 = logits[2 * NN + n];
  const float mx = fmaxf(l0, fmaxf(l1, l2));
  const float e0 = expf(l0 - mx), e1 = expf(l1 - mx), e2 = expf(l2 - mx);
  const float inv = 1.0f / (e0 + e1 + e2);
  const float a0 = e0 * inv, a1 = e1 * inv, a2 = e2 * inv;
  const size_t base = (size_t)n * 1536;
  float pre[4], s = 0.f, s2 = 0.f;
#pragma unroll
  for (int q4 = 0; q4 < 4; ++q4) {
    const int j = ln + (q4 << 6);
    const float v = a0 * b2f(rel_cat[base + 2 * 256 + j])
                  + a1 * b2f(rel_cat[base + 4 * 256 + j])
                  + a2 * b2f(rel_cat[base + 1 * 256 + j]);
    pre[q4] = v; s += v; s2 += v * v;
  }
#pragma unroll
  for (int off = 32; off > 0; off >>= 1) { s += __shfl_down(s, off, 64); s2 += __shfl_down(s2, off, 64); }
  s = __shfl(s, 0, 64); s2 = __shfl(s2, 0, 64);
  const float mu = s * (1.0f / 256.0f);
  const float var = s2 * (1.0f / 256.0f) - mu * mu;
  const float rs = rsqrtf(var + 1e-5f);
#pragma unroll
  for (int q4 = 0; q4 < 4; ++q4) {
    const int j = ln + (q4 << 6);
    comb[(size_t)n * 512 + 256 + j] = f2b((pre[q4] - mu) * rs * gmeta[j] + bmeta[j]);
  }
}

// final: out = LN(x + combined)
__global__ void final_k(const float* __restrict__ x, const float* __restrict__ combined,
                        const float* __restrict__ g, const float* __restrict__ b,
                        float* __restrict__ out)
{
  __shared__ float sred[8];
  const int n = blockIdx.x, t = threadIdx.x;
  const float v = x[(size_t)n * HH + t] + combined[(size_t)n * HH + t];
  float s = v, s2 = v * v;
#pragma unroll
  for (int off = 32; off > 0; off >>= 1) { s += __shfl_down(s, off, 64); s2 += __shfl_down(s2, off, 64); }
  const int wv = t >> 6;
  if ((t & 63) == 0) { sred[wv] = s; sred[4 + wv] = s2; }
  __syncthreads();
  const float st = sred[0] + sred[1] + sred[2] + sred[3];
  const float st2 = sred[4] + sred[5] + sred[6] + sred[7];
  const float mu = st * (1.0f / 256.0f);
  const float var = st2 * (1.0f / 256.0f) - mu * mu;
  const float rs = rsqrtf(var + 1e-5f);
  out[(size_t)n * HH + t] = (v - mu) * rs * g[t] + b[t];
}

// ---------------------------------------------------------------------------
extern "C" void kernel_launch(void* const* d_in, const int* in_sizes, int n_in,
                              void* d_out, int out_size, void* d_ws, size_t ws_size,
                              hipStream_t stream)
{
  const float* x      = (const float*)d_in[0];
  const int*   eidx   = (const int*)d_in[1];
  const float* eattr  = (const float*)d_in[2];
  const float* Wq     = (const float*)d_in[3];
  const float* bq     = (const float*)d_in[4];
  const float* Wk     = (const float*)d_in[5];
  const float* bk     = (const float*)d_in[6];
  const float* Wv     = (const float*)d_in[7];
  const float* bv     = (const float*)d_in[8];
  const float* prior  = (const float*)d_in[9];
  const float* Wm     = (const float*)d_in[10];
  const float* bm     = (const float*)d_in[11];
  const float* W_ir1  = (const float*)d_in[12];
  const float* b_ir1  = (const float*)d_in[13];
  const float* W_ir2  = (const float*)d_in[14];
  const float* b_ir2  = (const float*)d_in[15];
  const float* Wmp    = (const float*)d_in[16];
  const float* bmp    = (const float*)d_in[17];
  const float* Wa1    = (const float*)d_in[18];
  const float* ba1    = (const float*)d_in[19];
  const float* Wa2    = (const float*)d_in[20];
  const float* g_meta = (const float*)d_in[21];
  const float* b_meta = (const float*)d_in[22];
  const float* Wc     = (const float*)d_in[23];
  const float* bc     = (const float*)d_in[24];
  const float* g_out  = (const float*)d_in[25];
  const float* b_out  = (const float*)d_in[26];
  float* out = (float*)d_out;

  // ---- workspace layout: TOTAL 222,913,536 B (< 235.88 MB proven safe) ----
  char* ws = (char*)d_ws;
  bf16* rel_cat = (bf16*)ws;                         // [N][1536] bf16 = 153,600,000
  char* W0 = ws + 153600000;                         // weights: 4,861,952
  bf16*  Wqt   = (bf16*)(W0 + 0);          // [1536][256]   (6 relations stacked on NC)
  bf16*  Wkvt  = (bf16*)(W0 + 786432);     // [6][512][288] (k rows 0..255, v rows 256..511)
  bf16*  Wmt   = (bf16*)(W0 + 2555904);    // [6][256][256]
  bf16*  Wir1t = (bf16*)(W0 + 3342336);    // [256][1536]
  bf16*  Wct   = (bf16*)(W0 + 4128768);    // [256][512]
  bf16*  Wmpt  = (bf16*)(W0 + 4390912);    // [3][256][256]
  bf16*  Wa1t  = (bf16*)(W0 + 4784128);    // [128][256]
  float* bkv   = (float*)(W0 + 4849664);   // [6][512] fp32 (end 4,861,952)
  char* region = ws + 158461952;                     // 64,451,584 B
  // phase-1 views
  bf16*     kvbuf = (bf16*)(region + 0);             // [E][512] bf16 = 33,554,432
  float*    sc    = (float*)(region + 59154432);     //  1,048,576
  float*    exb   = (float*)(region + 60203008);     //  1,048,576
  unsigned* mkey  = (unsigned*)(region + 61251584);  //  1,600,000
  float*    denom = (float*)(region + 62851584);     //  1,600,000 (end 64,451,584)
  float*    agg   = out;                             // d_out as fp32 accumulator (phase 1)
  // phase-2 overlay (kvbuf dead)
  bf16*  hbuf     = (bf16*)(region + 0);             // 25,600,000
  float* interw   = (float*)(region + 59154432);     //  1,200,000 (sc/exb slots)
  // phase-3 overlay
  bf16*  tmp      = (bf16*)(region + 25600000);      // 25,600,000 (end 51,200,000)
  float* logits   = (float*)(region + 61251584);     //    600,000 (mkey slot)
  // phase-5
  bf16*  comb     = (bf16*)out;                      // [N][512] bf16 in d_out
  float* combined = (float*)(region + 0);            // [N][256] fp32 (phase-1/3 slots dead)

  const dim3 gN(391, 2);    // M=50000, NC=256
  const dim3 gQ(391, 12);   // M=50000, NC=1536 (batched q)
  const dim3 gKV(256, 4);   // M=32768, NC=512 (k||v)
  const dim3 gL(391, 1);    // M=50000, NC=128 (logits)

  // ---- phase 0: weight transpose/convert ----
  tconv_k<<<dim3(8, 8, 6), 256, 0, stream>>>(Wq, Wqt, 256, 256, 256, 256 * 256, 256 * 256);
  tconv_k<<<dim3(9, 8, 6), 256, 0, stream>>>(Wk, Wkvt, 272, 256, 288, 272 * 256, 512 * 288);
  tconv_k<<<dim3(9, 8, 6), 256, 0, stream>>>(Wv, Wkvt + 256 * 288, 272, 256, 288, 272 * 256, 512 * 288);
  tconv_k<<<dim3(8, 8, 6), 256, 0, stream>>>(Wm, Wmt, 256, 256, 256, 256 * 256, 256 * 256);
  tconv_k<<<dim3(48, 8, 1), 256, 0, stream>>>(W_ir1, Wir1t, 1536, 256, 1536, 0, 0);
  tconv_k<<<dim3(16, 8, 1), 256, 0, stream>>>(Wc, Wct, 512, 256, 512, 0, 0);
  tconv_k<<<dim3(8, 8, 3), 256, 0, stream>>>(Wmp, Wmpt, 256, 256, 256, 256 * 256, 256 * 256);
  tconv_k<<<dim3(8, 4, 1), 256, 0, stream>>>(Wa1, Wa1t, 256, 128, 256, 0, 0);
  bkv_k<<<12, 256, 0, stream>>>(bk, bv, bkv);

  // ---- phase 1a: ALL q in one GEMM, written into rel_cat (slot r = q_r).
  // Each slot is consumed by scores_k(r) BEFORE the Wm GEMM overwrites it. ----
  mm_k<1, 0, false, bf16><<<gQ, 256, 0, stream>>>(
      x, nullptr, 256, nullptr, nullptr,
      Wqt, bq, nullptr, rel_cat, 1536, nullptr, NN, 256);

  // ---- phase 1b: per-relation attention ----
  for (int r = 0; r < RR; ++r) {
    const int* src = eidx + (size_t)r * 2 * EE;
    const int* dst = src + EE;
    const float* ea = eattr + (size_t)r * EE * FF;
    zero_k<<<391, 256, 0, stream>>>((uint4*)mkey, (2 * NN * NHEAD * 4) / 16);  // mkey+denom contiguous
    zero_k<<<2048, 256, 0, stream>>>((uint4*)agg, (NN * HH * 4) / 16);
    // k||v = [x[src]||eattr||0] @ Wkv[r]  (gather in staging, NC=512)
    mm_k<3, 0, false, bf16><<<gKV, 256, 0, stream>>>(
        x, nullptr, 0, src, ea,
        Wkvt + (size_t)r * 512 * KVP, bkv + r * 512, nullptr, kvbuf, 512, nullptr, EE, KVP);
    scores_k<<<EE, 256, 0, stream>>>(rel_cat + r * 256, kvbuf, dst, prior + r * NHEAD, sc, mkey);
    expden_k<<<(EE * NHEAD + 255) / 256, 256, 0, stream>>>(sc, dst, mkey, exb, denom);
    agg_k<<<EE, 256, 0, stream>>>(exb, denom, kvbuf, dst, agg);
    // rel[r] = gelu(agg @ Wm[r] + bm[r]) -> rel_cat slot r (q_r is dead by now)
    mm_k<1, 1, false, bf16><<<gN, 256, 0, stream>>>(
        agg, nullptr, 256, nullptr, nullptr,
        Wmt + (size_t)r * 256 * 256, bm + r * HH, nullptr,
        rel_cat + r * 256, 1536, nullptr, NN, 256);
  }

  // ---- phase 2: inter-relation chain (consumes rel_cat BEFORE meta overwrites) ----
  mm_k<0, 1, false, bf16><<<gN, 256, 0, stream>>>(
      rel_cat, nullptr, 1536, nullptr, nullptr,
      Wir1t, b_ir1, nullptr, hbuf, 256, nullptr, NN, 1536);
  interw_k<<<(NN + 3) / 4, 256, 0, stream>>>(hbuf, W_ir2, b_ir2, interw);
  interagg_k<<<NN, 256, 0, stream>>>(interw, rel_cat, comb);

  // ---- phase 3: meta-path chain (in-place into rel_cat slots {2,4,1}) ----
  const int r1[3] = {2, 4, 1};
  const int r2[3] = {3, 0, 5};
  zero_k<<<147, 256, 0, stream>>>((uint4*)logits, (3 * NN * 4) / 16);
  for (int p = 0; p < 3; ++p) {
    // tmp = (rel[r1]+rel[r2]) @ Wmp[p] + bmp[p]
    mm_k<2, 0, false, bf16><<<gN, 256, 0, stream>>>(
        rel_cat + r1[p] * 256, rel_cat + r2[p] * 256, 1536, nullptr, nullptr,
        Wmpt + (size_t)p * 256 * 256, bmp + p * 256, nullptr, tmp, 256, nullptr, NN, 256);
    // logits[p] = sum_i tanh(tmp @ Wa1 + ba1)_i * Wa2_i
    mm_k<0, 0, true, bf16><<<gL, 256, 0, stream>>>(
        tmp, nullptr, 256, nullptr, nullptr,
        Wa1t, ba1, Wa2, (bf16*)nullptr, 0, logits + (size_t)p * NN, NN, 256);
    // write stacked[p] back into (now dead) rel_cat slot r1[p]
    copyslot_k<<<(NN * 32 + 255) / 256, 256, 0, stream>>>(tmp, rel_cat + r1[p] * 256);
  }
  metafinal_k<<<(NN + 3) / 4, 256, 0, stream>>>(logits, rel_cat, g_meta, b_meta, comb);

  // ---- phase 4: combine + output LN (d_out) ----
  mm_k<0, 1, false, float><<<gN, 256, 0, stream>>>(
      comb, nullptr, 512, nullptr, nullptr,
      Wct, bc, nullptr, combined, 256, nullptr, NN, 512);
  final_k<<<NN, 256, 0, stream>>>(x, combined, g_out, b_out, out);
}

// Round 6
// 1584.434 us; speedup vs baseline: 3.0099x; 1.1221x over previous
//
#include <hip/hip_runtime.h>
#include <hip/hip_bf16.h>

typedef __hip_bfloat16 bf16;
typedef __attribute__((ext_vector_type(8))) short short8;
typedef __attribute__((ext_vector_type(4))) float f32x4;

#define NN 50000
#define RR 6
#define EE 32768
#define HH 256
#define FF 16
#define NHEAD 8
#define KVP 320   // 272 padded to multiple of 64

struct __align__(8) bf16x4 { bf16 v[4]; };

__device__ __forceinline__ float b2f(bf16 v) { return __bfloat162float(v); }
__device__ __forceinline__ bf16 f2b(float v) { return __float2bfloat16(v); }
__device__ __forceinline__ short f2s(float f) { bf16 b = f2b(f); return __builtin_bit_cast(short, b); }
__device__ __forceinline__ float s2f(short s) { return b2f(__builtin_bit_cast(bf16, s)); }
__device__ __forceinline__ float gelu_f(float x) { return 0.5f * x * (1.0f + erff(x * 0.7071067811865476f)); }
__device__ __forceinline__ unsigned fkey(float f) { unsigned u = __float_as_uint(f); return (u & 0x80000000u) ? ~u : (u | 0x80000000u); }
__device__ __forceinline__ float fdec(unsigned k) { unsigned u = (k & 0x80000000u) ? (k & 0x7fffffffu) : ~k; return __uint_as_float(u); }

// async global->LDS, 16B per lane (dest = wave-uniform base + lane*16)
__device__ __forceinline__ void gl2lds16(const void* g, void* l) {
  __builtin_amdgcn_global_load_lds(
      (const __attribute__((address_space(1))) unsigned int*)g,
      (__attribute__((address_space(3))) unsigned int*)l, 16, 0, 0);
}

// grid-stride zero fill (16B granules)
__global__ void zero_k(uint4* __restrict__ p, int n16)
{
  const uint4 z = make_uint4(0u, 0u, 0u, 0u);
  for (int i = blockIdx.x * blockDim.x + threadIdx.x; i < n16; i += gridDim.x * blockDim.x)
    p[i] = z;
}

// fp32 -> bf16 elementwise (4 per thread)
__global__ void cvt_k(const float* __restrict__ in, bf16* __restrict__ out, int n4)
{
  const int i = blockIdx.x * 256 + threadIdx.x;
  if (i >= n4) return;
  const float4 f = ((const float4*)in)[i];
  bf16x4 o; o.v[0] = f2b(f.x); o.v[1] = f2b(f.y); o.v[2] = f2b(f.z); o.v[3] = f2b(f.w);
  ((bf16x4*)out)[i] = o;
}

// transpose-convert: in fp32 [K][NC] -> out bf16 [NC][Kp], zero-pad K..Kp.
// batch via z with explicit element strides (izs for in, ozs for out).
__global__ void tconv_k(const float* __restrict__ in, bf16* __restrict__ out,
                        int K, int NC, int Kp, long izs, long ozs)
{
  __shared__ float t[32][33];
  in  += (size_t)blockIdx.z * izs;
  out += (size_t)blockIdx.z * ozs;
  const int kb = blockIdx.x * 32, nb = blockIdx.y * 32;
  const int tx = threadIdx.x & 31, ty = threadIdx.x >> 5;  // ty 0..7
  for (int i = ty; i < 32; i += 8) {
    const int k = kb + i, n = nb + tx;
    t[i][tx] = (k < K && n < NC) ? in[(size_t)k * NC + n] : 0.f;
  }
  __syncthreads();
  for (int i = ty; i < 32; i += 8) {
    const int n = nb + i, k = kb + tx;
    if (n < NC && k < Kp) out[(size_t)n * Kp + k] = f2b(t[tx][i]);
  }
}

// build concatenated kv bias: bkv[r][0..255]=bk[r], bkv[r][256..511]=bv[r]
__global__ void bkv_k(const float* __restrict__ bk, const float* __restrict__ bv,
                      float* __restrict__ bkv)
{
  const int i = blockIdx.x * 256 + threadIdx.x;
  if (i >= RR * 512) return;
  const int r = i >> 9, c = i & 511;
  bkv[i] = (c < 256) ? bk[r * 256 + c] : bv[r * 256 + (c - 256)];
}

// copy tmp [N][256] bf16 -> rel_cat slot (ld 1536)
__global__ void copyslot_k(const bf16* __restrict__ tmp, bf16* __restrict__ slot)
{
  const int i = blockIdx.x * 256 + threadIdx.x;  // 8-elem chunk id
  if (i >= NN * 32) return;
  const int n = i >> 5, c = (i & 31) * 8;
  *(short8*)(slot + (size_t)n * 1536 + c) = *(const short8*)(tmp + (size_t)n * 256 + c);
}

// ---------------------------------------------------------------------------
// MFMA GEMM: C[M,NC] = act(A[M,K] @ Bt^T + bias), Bt = [NC][K] bf16 k-contig.
// 128x128 tile, BK=64, 4 waves, each wave 64x64 (4x4 of 16x16x32 MFMA).
// Grid: blockIdx.x = col tile, blockIdx.y = row tile (A reuse across x).
// LDS chunk (row, cg) holds global chunk cg ^ (row&7): staging stays
// lane-contiguous (gl2lds16-legal) while fragment reads spread all 32 banks.
// ASRC: 0=A bf16 async; 1=A fp32, convert in staging; 2=PAIR bf16 sum;
//       3=KV gather: xb bf16 via src + eattr fp32 + zero pad.
// LOGITS: A = rel_cat + slot[z]*256; epilogue atomicAdd(logits[z*M+row],
//         sum_col tanh(c+bias[col])*wa2[col]).
// ---------------------------------------------------------------------------
template<int ASRC, int ACT, bool LOGITS, typename TO>
__global__ __launch_bounds__(256) void mm_k(
    const void* __restrict__ Av, const bf16* __restrict__ A2, int lda,
    const int* __restrict__ src, const float* __restrict__ eattr,
    const bf16* __restrict__ Bt, const float* __restrict__ bias,
    const float* __restrict__ wa2, TO* __restrict__ C, int ldc,
    float* __restrict__ logits, int M, int K)
{
  __shared__ short lA[128 * 64];
  __shared__ short lB[128 * 64];
  const int tid = threadIdx.x;
  const int w = tid >> 6, l = tid & 63;
  const int col0 = blockIdx.x << 7;
  const int row0 = blockIdx.y << 7;
  const bf16* Ab = (const bf16*)Av;
  float* lg = logits;
  if constexpr (LOGITS) {
    const int slots3[3] = {2, 4, 1};
    Ab = (const bf16*)Av + slots3[blockIdx.z] * 256;
    lg = logits + (size_t)blockIdx.z * M;
  }
  const int wm = (w >> 1) << 6, wn = (w & 1) << 6;
  const int lane15 = l & 15, kq = l >> 4;

  f32x4 acc[4][4] = {};

  for (int k0 = 0; k0 < K; k0 += 64) {
    // stage A tile [128][64] (swizzled chunks)
#pragma unroll
    for (int i = 0; i < 4; ++i) {
      const int idx = (w * 4 + i) * 64 + l;        // 0..1023 16B chunks
      const int row = idx >> 3, cg = idx & 7;
      const int scg = cg ^ (row & 7);
      const int r = min(row0 + row, M - 1);
      const int kc = k0 + scg * 8;
      if constexpr (ASRC == 0) {
        gl2lds16(Ab + (size_t)r * lda + kc, &lA[idx * 8]);
      } else if constexpr (ASRC == 1) {
        const float* p = (const float*)Av + (size_t)r * lda + kc;
        const float4 f0 = *(const float4*)p;
        const float4 f1 = *(const float4*)(p + 4);
        short8 s;
        s[0] = f2s(f0.x); s[1] = f2s(f0.y); s[2] = f2s(f0.z); s[3] = f2s(f0.w);
        s[4] = f2s(f1.x); s[5] = f2s(f1.y); s[6] = f2s(f1.z); s[7] = f2s(f1.w);
        *(short8*)&lA[idx * 8] = s;
      } else if constexpr (ASRC == 2) {
        const short8 u = *(const short8*)((const bf16*)Av + (size_t)r * lda + kc);
        const short8 v2 = *(const short8*)(A2 + (size_t)r * lda + kc);
        short8 s;
#pragma unroll
        for (int j = 0; j < 8; ++j) s[j] = f2s(s2f(u[j]) + s2f(v2[j]));
        *(short8*)&lA[idx * 8] = s;
      } else {  // ASRC == 3: kv gather from xb (bf16) + eattr (fp32) + pad
        short8 s;
        if (kc < HH) {
          s = *(const short8*)((const bf16*)Av + (size_t)src[r] * HH + kc);
        } else if (kc < HH + FF) {
          const float* p = eattr + (size_t)r * FF + (kc - HH);
          const float4 f0 = *(const float4*)p;
          const float4 f1 = *(const float4*)(p + 4);
          s[0] = f2s(f0.x); s[1] = f2s(f0.y); s[2] = f2s(f0.z); s[3] = f2s(f0.w);
          s[4] = f2s(f1.x); s[5] = f2s(f1.y); s[6] = f2s(f1.z); s[7] = f2s(f1.w);
        } else {
#pragma unroll
          for (int j = 0; j < 8; ++j) s[j] = 0;
        }
        *(short8*)&lA[idx * 8] = s;
      }
    }
    // stage B tile [128][64] (swizzled, async; block's 128 cols always in range)
#pragma unroll
    for (int i = 0; i < 4; ++i) {
      const int idx = (w * 4 + i) * 64 + l;
      const int row = idx >> 3, cg = idx & 7;
      const int scg = cg ^ (row & 7);
      gl2lds16(Bt + (size_t)(col0 + row) * K + k0 + scg * 8, &lB[idx * 8]);
    }
    __syncthreads();
#pragma unroll
    for (int kk = 0; kk < 64; kk += 32) {
      short8 af[4], bfr[4];
#pragma unroll
      for (int t = 0; t < 4; ++t) {
        const int ra = wm + t * 16 + lane15;
        const int ca = ((kk >> 3) + kq) ^ (ra & 7);
        af[t] = *(const short8*)&lA[ra * 64 + ca * 8];
        const int rb = wn + t * 16 + lane15;
        const int cb = ((kk >> 3) + kq) ^ (rb & 7);
        bfr[t] = *(const short8*)&lB[rb * 64 + cb * 8];
      }
#pragma unroll
      for (int ti = 0; ti < 4; ++ti)
#pragma unroll
        for (int tj = 0; tj < 4; ++tj)
          acc[ti][tj] = __builtin_amdgcn_mfma_f32_16x16x32_bf16(af[ti], bfr[tj], acc[ti][tj], 0, 0, 0);
    }
    __syncthreads();
  }

  if constexpr (!LOGITS) {
    // C layout: col = lane&15, row = (lane>>4)*4 + reg  [m89-verified]
#pragma unroll
    for (int ti = 0; ti < 4; ++ti) {
#pragma unroll
      for (int reg = 0; reg < 4; ++reg) {
        const int row = row0 + wm + ti * 16 + kq * 4 + reg;
        if (row >= M) continue;
#pragma unroll
        for (int tj = 0; tj < 4; ++tj) {
          const int col = col0 + wn + tj * 16 + lane15;
          float v = acc[ti][tj][reg] + bias[col];
          if constexpr (ACT == 1) v = gelu_f(v);
          if constexpr (sizeof(TO) == 2) C[(size_t)row * ldc + col] = (TO)f2b(v);
          else                           C[(size_t)row * ldc + col] = (TO)v;
        }
      }
    }
  } else {
#pragma unroll
    for (int ti = 0; ti < 4; ++ti) {
#pragma unroll
      for (int reg = 0; reg < 4; ++reg) {
        float part = 0.f;
#pragma unroll
        for (int tj = 0; tj < 4; ++tj) {
          const int col = col0 + wn + tj * 16 + lane15;
          part += tanhf(acc[ti][tj][reg] + bias[col]) * wa2[col];
        }
#pragma unroll
        for (int off = 8; off > 0; off >>= 1) part += __shfl_xor(part, off, 64);
        const int row = row0 + wm + ti * 16 + kq * 4 + reg;
        if (lane15 == 0 && row < M) atomicAdd(&lg[row], part);
      }
    }
  }
}

// ---------------------------------------------------------------------------
// Edge-side kernels; q lives in rel_cat (ld 1536, slot r), k/v in kv [E][512]
// ---------------------------------------------------------------------------
__global__ void scores_k(const bf16* __restrict__ q, const bf16* __restrict__ kv,
                         const int* __restrict__ dst_idx, const float* __restrict__ prior_r,
                         float* __restrict__ scores, unsigned* __restrict__ mkey)
{
  const int e = blockIdx.x, t = threadIdx.x;
  const int dst = dst_idx[e];
  float p = b2f(q[(size_t)dst * 1536 + t]) * b2f(kv[(size_t)e * 512 + t]);
#pragma unroll
  for (int off = 16; off > 0; off >>= 1) p += __shfl_down(p, off, 32);
  const int h = t >> 5;
  if ((t & 31) == 0) {
    const float s = p * 0.1767766952966369f * prior_r[h];
    scores[e * NHEAD + h] = s;
    atomicMax(&mkey[dst * NHEAD + h], fkey(s));
  }
}

__global__ void expden_k(const float* __restrict__ scores, const int* __restrict__ dst_idx,
                         const unsigned* __restrict__ mkey, float* __restrict__ ex,
                         float* __restrict__ denom)
{
  const int idx = blockIdx.x * 256 + threadIdx.x;
  if (idx >= EE * NHEAD) return;
  const int e = idx >> 3, h = idx & 7;
  const int dst = dst_idx[e];
  const float m = fdec(mkey[dst * NHEAD + h]);
  const float v = expf(scores[idx] - m);
  ex[idx] = v;
  atomicAdd(&denom[dst * NHEAD + h], v);
}

__global__ void agg_k(const float* __restrict__ ex, const float* __restrict__ denom,
                      const bf16* __restrict__ kv, const int* __restrict__ dst_idx,
                      float* __restrict__ agg)
{
  const int e = blockIdx.x, t = threadIdx.x, h = t >> 5;
  const int dst = dst_idx[e];
  const float w = ex[e * NHEAD + h] / (denom[dst * NHEAD + h] + 1e-16f);
  atomicAdd(&agg[(size_t)dst * HH + t], w * b2f(kv[(size_t)e * 512 + 256 + t]));
}

// ---------------------------------------------------------------------------
// inter-relation softmax weights; one wave per node
// ---------------------------------------------------------------------------
__global__ void interw_k(const bf16* __restrict__ h, const float* __restrict__ W2,
                         const float* __restrict__ b2, float* __restrict__ interw)
{
  const int wv = threadIdx.x >> 6, ln = threadIdx.x & 63;
  const int n = blockIdx.x * 4 + wv;
  if (n >= NN) return;
  float a[6] = {0.f, 0.f, 0.f, 0.f, 0.f, 0.f};
#pragma unroll
  for (int kq = 0; kq < 4; ++kq) {
    const int k = ln + (kq << 6);
    const float hv = b2f(h[(size_t)n * HH + k]);
#pragma unroll
    for (int j = 0; j < 6; ++j) a[j] += hv * W2[k * 6 + j];
  }
#pragma unroll
  for (int j = 0; j < 6; ++j) {
#pragma unroll
    for (int off = 32; off > 0; off >>= 1) a[j] += __shfl_down(a[j], off, 64);
  }
  if (ln == 0) {
    float lg[6], e[6], mx = -1e30f, s = 0.f;
#pragma unroll
    for (int j = 0; j < 6; ++j) { lg[j] = a[j] + b2[j]; mx = fmaxf(mx, lg[j]); }
#pragma unroll
    for (int j = 0; j < 6; ++j) { e[j] = expf(lg[j] - mx); s += e[j]; }
    const float inv = 1.0f / s;
#pragma unroll
    for (int j = 0; j < 6; ++j) interw[(size_t)n * 6 + j] = e[j] * inv;
  }
}

// rel_cat layout: [N][R*256]
__global__ void interagg_k(const float* __restrict__ interw, const bf16* __restrict__ rel_cat,
                           bf16* __restrict__ comb)
{
  const int n = blockIdx.x, t = threadIdx.x;
  float acc = 0.f;
#pragma unroll
  for (int r = 0; r < 6; ++r)
    acc += interw[(size_t)n * 6 + r] * b2f(rel_cat[(size_t)n * 1536 + r * 256 + t]);
  comb[(size_t)n * 512 + t] = f2b(acc);
}

// ---------------------------------------------------------------------------
// meta final: softmax(logits[3]) -> weighted sum of stacked -> LN -> comb[:,256:]
// stacked[p] lives in rel_cat slots {2,4,1} (ld 1536); logits = [3][N] fp32
// ---------------------------------------------------------------------------
__global__ void metafinal_k(const float* __restrict__ logits, const bf16* __restrict__ rel_cat,
                            const float* __restrict__ gmeta, const float* __restrict__ bmeta,
                            bf16* __restrict__ comb)
{
  const int wv = threadIdx.x >> 6, ln = threadIdx.x & 63;
  const int n = blockIdx.x * 4 + wv;
  if (n >= NN) return;
  const float l0 = logits[n], l1 = logits[NN + n], l2 = logits[2 * NN + n];
  const float mx = fmaxf(l0, fmaxf(l1, l2));
  const float e0 = expf(l0 - mx), e1 = expf(l1 - mx), e2 = expf(l2 - mx);
  const float inv = 1.0f / (e0 + e1 + e2);
  const float a0 = e0 * inv, a1 = e1 * inv, a2 = e2 * inv;
  const size_t base = (size_t)n * 1536;
  float pre[4], s = 0.f, s2 = 0.f;
#pragma unroll
  for (int q4 = 0; q4 < 4; ++q4) {
    const int j = ln + (q4 << 6);
    const float v = a0 * b2f(rel_cat[base + 2 * 256 + j])
                  + a1 * b2f(rel_cat[base + 4 * 256 + j])
                  + a2 * b2f(rel_cat[base + 1 * 256 + j]);
    pre[q4] = v; s += v; s2 += v * v;
  }
#pragma unroll
  for (int off = 32; off > 0; off >>= 1) { s += __shfl_down(s, off, 64); s2 += __shfl_down(s2, off, 64); }
  s = __shfl(s, 0, 64); s2 = __shfl(s2, 0, 64);
  const float mu = s * (1.0f / 256.0f);
  const float var = s2 * (1.0f / 256.0f) - mu * mu;
  const float rs = rsqrtf(var + 1e-5f);
#pragma unroll
  for (int q4 = 0; q4 < 4; ++q4) {
    const int j = ln + (q4 << 6);
    comb[(size_t)n * 512 + 256 + j] = f2b((pre[q4] - mu) * rs * gmeta[j] + bmeta[j]);
  }
}

// final: out = LN(x + combined)
__global__ void final_k(const float* __restrict__ x, const float* __restrict__ combined,
                        const float* __restrict__ g, const float* __restrict__ b,
                        float* __restrict__ out)
{
  __shared__ float sred[8];
  const int n = blockIdx.x, t = threadIdx.x;
  const float v = x[(size_t)n * HH + t] + combined[(size_t)n * HH + t];
  float s = v, s2 = v * v;
#pragma unroll
  for (int off = 32; off > 0; off >>= 1) { s += __shfl_down(s, off, 64); s2 += __shfl_down(s2, off, 64); }
  const int wv = t >> 6;
  if ((t & 63) == 0) { sred[wv] = s; sred[4 + wv] = s2; }
  __syncthreads();
  const float st = sred[0] + sred[1] + sred[2] + sred[3];
  const float st2 = sred[4] + sred[5] + sred[6] + sred[7];
  const float mu = st * (1.0f / 256.0f);
  const float var = st2 * (1.0f / 256.0f) - mu * mu;
  const float rs = rsqrtf(var + 1e-5f);
  out[(size_t)n * HH + t] = (v - mu) * rs * g[t] + b[t];
}

// ---------------------------------------------------------------------------
extern "C" void kernel_launch(void* const* d_in, const int* in_sizes, int n_in,
                              void* d_out, int out_size, void* d_ws, size_t ws_size,
                              hipStream_t stream)
{
  const float* x      = (const float*)d_in[0];
  const int*   eidx   = (const int*)d_in[1];
  const float* eattr  = (const float*)d_in[2];
  const float* Wq     = (const float*)d_in[3];
  const float* bq     = (const float*)d_in[4];
  const float* Wk     = (const float*)d_in[5];
  const float* bk     = (const float*)d_in[6];
  const float* Wv     = (const float*)d_in[7];
  const float* bv     = (const float*)d_in[8];
  const float* prior  = (const float*)d_in[9];
  const float* Wm     = (const float*)d_in[10];
  const float* bm     = (const float*)d_in[11];
  const float* W_ir1  = (const float*)d_in[12];
  const float* b_ir1  = (const float*)d_in[13];
  const float* W_ir2  = (const float*)d_in[14];
  const float* b_ir2  = (const float*)d_in[15];
  const float* Wmp    = (const float*)d_in[16];
  const float* bmp    = (const float*)d_in[17];
  const float* Wa1    = (const float*)d_in[18];
  const float* ba1    = (const float*)d_in[19];
  const float* Wa2    = (const float*)d_in[20];
  const float* g_meta = (const float*)d_in[21];
  const float* b_meta = (const float*)d_in[22];
  const float* Wc     = (const float*)d_in[23];
  const float* bc     = (const float*)d_in[24];
  const float* g_out  = (const float*)d_in[25];
  const float* b_out  = (const float*)d_in[26];
  float* out = (float*)d_out;

  // ---- workspace layout: PEAK 223,110,144 B (< 235.88 MB proven safe) ----
  char* ws = (char*)d_ws;
  bf16* rel_cat = (bf16*)ws;                         // [N][1536] bf16 = 153,600,000
  char* W0 = ws + 153600000;                         // weights: 5,058,560
  bf16*  Wqt   = (bf16*)(W0 + 0);          // [1536][256]   (6 relations stacked on NC)
  bf16*  Wkvt  = (bf16*)(W0 + 786432);     // [6][512][320] (k rows 0..255, v rows 256..511)
  bf16*  Wmt   = (bf16*)(W0 + 2752512);    // [6][256][256]
  bf16*  Wir1t = (bf16*)(W0 + 3538944);    // [256][1536]
  bf16*  Wct   = (bf16*)(W0 + 4325376);    // [256][512]
  bf16*  Wmpt  = (bf16*)(W0 + 4587520);    // [3][256][256]
  bf16*  Wa1t  = (bf16*)(W0 + 4980736);    // [128][256]
  float* bkv   = (float*)(W0 + 5046272);   // [6][512] fp32 (end 5,058,560)
  char* region = ws + 158658560;
  // phase-1 views
  bf16*     kvbuf = (bf16*)(region + 0);             // [E][512] bf16 = 33,554,432
  float*    sc    = (float*)(region + 33554432);     //  1,048,576
  float*    exb   = (float*)(region + 34603008);     //  1,048,576
  unsigned* mkey  = (unsigned*)(region + 35651584);  //  1,600,000
  float*    denom = (float*)(region + 37251584);     //  1,600,000 (contig w/ mkey)
  bf16*     xb    = (bf16*)(region + 38851584);      // [N][256] bf16 = 25,600,000 (end 64,451,584)
  float*    agg   = out;                             // d_out as fp32 accumulator (phase 1)
  // phase-2 overlay (kvbuf dead)
  bf16*  hbuf     = (bf16*)(region + 0);             // 25,600,000
  float* interw   = (float*)(region + 33554432);     //  1,200,000 (sc/exb slots)
  // phase-3 overlay (hbuf/interw/xb dead)
  bf16*  tmp      = (bf16*)(region + 25600000);      // 25,600,000 (end 51,200,000)
  float* logits   = (float*)(region + 51200000);     //    600,000 (end 51,800,000)
  // phase-5
  bf16*  comb     = (bf16*)out;                      // [N][512] bf16 in d_out
  float* combined = (float*)(region + 0);            // [N][256] fp32 (tmp/hbuf dead; logits above)

  // grids: x = col tiles, y = row tiles (A-tile L2 reuse across x)
  const dim3 gN(2, 391);     // M=50000, NC=256
  const dim3 gQ(12, 391);    // M=50000, NC=1536 (batched q)
  const dim3 gKV(4, 256);    // M=32768, NC=512 (k||v)
  const dim3 gL(1, 391, 3);  // M=50000, NC=128, z=3 meta-paths (logits)

  // ---- phase 0: weight transpose/convert + x->bf16 ----
  tconv_k<<<dim3(8, 8, 6), 256, 0, stream>>>(Wq, Wqt, 256, 256, 256, 256 * 256, 256 * 256);
  tconv_k<<<dim3(10, 8, 6), 256, 0, stream>>>(Wk, Wkvt, 272, 256, 320, 272 * 256, 512 * 320);
  tconv_k<<<dim3(10, 8, 6), 256, 0, stream>>>(Wv, Wkvt + 256 * 320, 272, 256, 320, 272 * 256, 512 * 320);
  tconv_k<<<dim3(8, 8, 6), 256, 0, stream>>>(Wm, Wmt, 256, 256, 256, 256 * 256, 256 * 256);
  tconv_k<<<dim3(48, 8, 1), 256, 0, stream>>>(W_ir1, Wir1t, 1536, 256, 1536, 0, 0);
  tconv_k<<<dim3(16, 8, 1), 256, 0, stream>>>(Wc, Wct, 512, 256, 512, 0, 0);
  tconv_k<<<dim3(8, 8, 3), 256, 0, stream>>>(Wmp, Wmpt, 256, 256, 256, 256 * 256, 256 * 256);
  tconv_k<<<dim3(8, 4, 1), 256, 0, stream>>>(Wa1, Wa1t, 256, 128, 256, 0, 0);
  bkv_k<<<12, 256, 0, stream>>>(bk, bv, bkv);
  cvt_k<<<(NN * 64 + 255) / 256, 256, 0, stream>>>(x, xb, NN * 64);

  // ---- phase 1a: ALL q in one GEMM (bf16 A, pure async staging) -> rel_cat.
  // Slot r is consumed by scores_k(r) BEFORE the Wm GEMM overwrites it. ----
  mm_k<0, 0, false, bf16><<<gQ, 256, 0, stream>>>(
      xb, nullptr, 256, nullptr, nullptr,
      Wqt, bq, nullptr, rel_cat, 1536, nullptr, NN, 256);

  // ---- phase 1b: per-relation attention ----
  for (int r = 0; r < RR; ++r) {
    const int* src = eidx + (size_t)r * 2 * EE;
    const int* dst = src + EE;
    const float* ea = eattr + (size_t)r * EE * FF;
    zero_k<<<391, 256, 0, stream>>>((uint4*)mkey, (2 * NN * NHEAD * 4) / 16);  // mkey+denom
    zero_k<<<2048, 256, 0, stream>>>((uint4*)agg, (NN * HH * 4) / 16);
    // k||v = [xb[src]||eattr||0] @ Wkv[r]  (gather in staging, NC=512, K=320)
    mm_k<3, 0, false, bf16><<<gKV, 256, 0, stream>>>(
        xb, nullptr, 0, src, ea,
        Wkvt + (size_t)r * 512 * KVP, bkv + r * 512, nullptr, kvbuf, 512, nullptr, EE, KVP);
    scores_k<<<EE, 256, 0, stream>>>(rel_cat + r * 256, kvbuf, dst, prior + r * NHEAD, sc, mkey);
    expden_k<<<(EE * NHEAD + 255) / 256, 256, 0, stream>>>(sc, dst, mkey, exb, denom);
    agg_k<<<EE, 256, 0, stream>>>(exb, denom, kvbuf, dst, agg);
    // rel[r] = gelu(agg @ Wm[r] + bm[r]) -> rel_cat slot r (q_r is dead by now)
    mm_k<1, 1, false, bf16><<<gN, 256, 0, stream>>>(
        agg, nullptr, 256, nullptr, nullptr,
        Wmt + (size_t)r * 256 * 256, bm + r * HH, nullptr,
        rel_cat + r * 256, 1536, nullptr, NN, 256);
  }

  // ---- phase 2: inter-relation chain (consumes rel_cat BEFORE meta overwrites) ----
  mm_k<0, 1, false, bf16><<<gN, 256, 0, stream>>>(
      rel_cat, nullptr, 1536, nullptr, nullptr,
      Wir1t, b_ir1, nullptr, hbuf, 256, nullptr, NN, 1536);
  interw_k<<<(NN + 3) / 4, 256, 0, stream>>>(hbuf, W_ir2, b_ir2, interw);
  interagg_k<<<NN, 256, 0, stream>>>(interw, rel_cat, comb);

  // ---- phase 3: meta-path chain ----
  const int r1[3] = {2, 4, 1};
  const int r2[3] = {3, 0, 5};
  for (int p = 0; p < 3; ++p) {
    // tmp = (rel[r1]+rel[r2]) @ Wmp[p] + bmp[p]
    mm_k<2, 0, false, bf16><<<gN, 256, 0, stream>>>(
        rel_cat + r1[p] * 256, rel_cat + r2[p] * 256, 1536, nullptr, nullptr,
        Wmpt + (size_t)p * 256 * 256, bmp + p * 256, nullptr, tmp, 256, nullptr, NN, 256);
    // write stacked[p] into (now dead) rel_cat slot r1[p]
    copyslot_k<<<(NN * 32 + 255) / 256, 256, 0, stream>>>(tmp, rel_cat + r1[p] * 256);
  }
  zero_k<<<147, 256, 0, stream>>>((uint4*)logits, (3 * NN * 4) / 16);
  // logits[z] = sum_i tanh(stacked[z] @ Wa1 + ba1)_i * Wa2_i  (z=3 batched)
  mm_k<0, 0, true, bf16><<<gL, 256, 0, stream>>>(
      rel_cat, nullptr, 1536, nullptr, nullptr,
      Wa1t, ba1, Wa2, (bf16*)nullptr, 0, logits, NN, 256);
  metafinal_k<<<(NN + 3) / 4, 256, 0, stream>>>(logits, rel_cat, g_meta, b_meta, comb);

  // ---- phase 4: combine + output LN (d_out) ----
  mm_k<0, 1, false, float><<<gN, 256, 0, stream>>>(
      comb, nullptr, 512, nullptr, nullptr,
      Wct, bc, nullptr, combined, 256, nullptr, NN, 512);
  final_k<<<NN, 256, 0, stream>>>(x, combined, g_out, b_out, out);
}